// Round 10
// baseline (340.135 us; speedup 1.0000x reference)
//
#include <hip/hip_runtime.h>

typedef _Float16 f16;
typedef f16 f16x8 __attribute__((ext_vector_type(8)));
typedef f16 f16x4 __attribute__((ext_vector_type(4)));
typedef __fp16 fp16x2 __attribute__((ext_vector_type(2)));
typedef float f32x4 __attribute__((ext_vector_type(4)));
typedef float f32x16 __attribute__((ext_vector_type(16)));
typedef unsigned int u32;

#define NTOK 4096

// async global->LDS, 16B per lane; dest = wave-uniform base + lane*16
#define GLL(gsrc, ldst) \
  __builtin_amdgcn_global_load_lds( \
      (const __attribute__((address_space(1))) void*)(gsrc), \
      (__attribute__((address_space(3))) void*)(ldst), 16, 0, 0)

// ---------------- fused f32 -> f16 convert (x | w_qkv | w_out) ----------------
__global__ __launch_bounds__(256) void k_cvt(
    const float* __restrict__ x, const float* __restrict__ wq,
    const float* __restrict__ wo,
    f16* __restrict__ xb, f16* __restrict__ wqb, f16* __restrict__ wob)
{
  const int bx = blockIdx.x;
  const float* src; f16* dst; int off;
  if (bx < 2048)      { src = x;  dst = xb;  off = bx * 1024; }
  else if (bx < 2240) { src = wq; dst = wqb; off = (bx - 2048) * 1024; }
  else                { src = wo; dst = wob; off = (bx - 2240) * 1024; }
  const int i = off + threadIdx.x * 4;
  float4 f = *(const float4*)(src + i);
  f16x4 h;
  h[0] = (f16)f.x; h[1] = (f16)f.y; h[2] = (f16)f.z; h[3] = (f16)f.w;
  *(f16x4*)(dst + i) = h;
}

// ---------------- generic C = A[M,K] * W[NC,K]^T MFMA GEMM ----------------
// mode 0: QKV epilogue -> scatter to Qb/Kb/Vtb + fused norm partial sums (f32 acc)
// mode 1: out epilogue -> d_out f32 + bias
__global__ __launch_bounds__(256) void k_gemm(
    const f16* __restrict__ A, const f16* __restrict__ W,
    int K, int mode,
    f16* __restrict__ Qb, f16* __restrict__ Kb, f16* __restrict__ Vtb,
    float* __restrict__ outF, const float* __restrict__ bias,
    float* __restrict__ partQ, float* __restrict__ partK)
{
  __shared__ f16 Al[64 * 40];
  __shared__ f16 Wl[64 * 40];
  __shared__ float redl[4][64];
  const int t = threadIdx.x;
  const int w = t >> 6, l = t & 63;
  const int lrow = l & 15, lk = l >> 4;
  const int m0 = blockIdx.y * 64, nc0 = blockIdx.x * 64;
  f32x4 acc[4] = {};
  const int srow = t >> 2, sseg = t & 3;
  for (int k0 = 0; k0 < K; k0 += 32) {
    __syncthreads();
    f16x8 av = *(const f16x8*)(A + (size_t)(m0 + srow) * K + k0 + sseg * 8);
    f16x8 wv = *(const f16x8*)(W + (size_t)(nc0 + srow) * K + k0 + sseg * 8);
    *(f16x8*)(Al + srow * 40 + sseg * 8) = av;
    *(f16x8*)(Wl + srow * 40 + sseg * 8) = wv;
    __syncthreads();
    f16x8 af = *(const f16x8*)(Al + (w * 16 + lrow) * 40 + lk * 8);
#pragma unroll
    for (int ct = 0; ct < 4; ++ct) {
      f16x8 bf = *(const f16x8*)(Wl + (ct * 16 + lrow) * 40 + lk * 8);
      acc[ct] = __builtin_amdgcn_mfma_f32_16x16x32_f16(af, bf, acc[ct], 0, 0, 0);
    }
  }
  const int nb = m0 + w * 16 + lk * 4;
  if (mode == 0) {
    const int b = nb >> 12, n = nb & 4095;
#pragma unroll
    for (int ct = 0; ct < 4; ++ct) {
      int gc = nc0 + ct * 16 + lrow;
      int s = gc >> 8, h = (gc >> 6) & 3, dd = gc & 63;
      int bh = b * 4 + h;
      if (s == 2) {
        f16x4 v;
#pragma unroll
        for (int j = 0; j < 4; ++j) v[j] = (f16)acc[ct][j];
        *(f16x4*)(Vtb + ((size_t)bh * 64 + dd) * 4096 + n) = v;
      } else {
        f16* dst = (s == 0) ? Qb : Kb;
#pragma unroll
        for (int j = 0; j < 4; ++j)
          dst[((size_t)bh * 4096 + n + j) * 64 + dd] = (f16)acc[ct][j];
      }
    }
    // fused per-channel squared-sum partials (over this block's 64 tokens)
    if (nc0 < 512) {
#pragma unroll
      for (int ct = 0; ct < 4; ++ct) {
        float v = acc[ct][0] * acc[ct][0] + acc[ct][1] * acc[ct][1]
                + acc[ct][2] * acc[ct][2] + acc[ct][3] * acc[ct][3];
        v += __shfl_xor(v, 16, 64);
        v += __shfl_xor(v, 32, 64);
        if (lk == 0) redl[w][ct * 16 + lrow] = v;
      }
      __syncthreads();
      if (t < 64) {
        float sq = redl[0][t] + redl[1][t] + redl[2][t] + redl[3][t];
        const int s = nc0 >> 8, h2 = (nc0 >> 6) & 3;
        const int b2 = m0 >> 12, mb = (m0 >> 6) & 63;
        float* dst = (s == 0) ? partQ : partK;
        dst[((b2 * 4 + h2) * 64 + mb) * 64 + t] = sq;
      }
    }
  } else {
#pragma unroll
    for (int ct = 0; ct < 4; ++ct) {
      int gc = nc0 + ct * 16 + lrow;
      float bv = bias[gc];
#pragma unroll
      for (int j = 0; j < 4; ++j)
        outF[(size_t)(nb + j) * 256 + gc] = acc[ct][j] + bv;
    }
  }
}

// ---------------- finalize: combined Q-side scale c = temp*log2e/(|q||k|) ----
__global__ __launch_bounds__(512) void k_norm2(
    const float* __restrict__ partQ, const float* __restrict__ partK,
    const float* __restrict__ temp, f16* __restrict__ cqh)
{
  const int t = threadIdx.x;            // 512 = 8 bh * 64 dd
  const int bh = t >> 6, dd = t & 63;
  float sq = 0.f, sk = 0.f;
  for (int s = 0; s < 64; ++s) {
    sq += partQ[(bh * 64 + s) * 64 + dd];
    sk += partK[(bh * 64 + s) * 64 + dd];
  }
  float c = temp[bh & 3] * 1.4426950408889634f /
            (fmaxf(sqrtf(sq), 1e-12f) * fmaxf(sqrtf(sk), 1e-12f));
  cqh[t] = (f16)c;
}

// ---------------- flash attention v7: QBLK=128 x key-split, 2 blocks/CU ------
// Grid 512 = 8 bh x 32 qt x 2 kv.  Block: 8 waves = 4 ks x 2 qh; wave owns
// 32-key slice x 64 queries (2 sets of 32) -> K/V frags reused across sets.
// 16 tiles of 128 keys, GLL dbuf.  Partials (f16 O, f32 ls) to global;
// k_comb merges the two kv halves.
__device__ inline void plane_swap(u32& a, u32& b) {
  asm volatile("v_permlane32_swap_b32 %0, %1" : "+v"(a), "+v"(b));
}

__global__ __launch_bounds__(512, 4) void k_flash7(
    const f16* __restrict__ Qb, const f16* __restrict__ Kb,
    const f16* __restrict__ Vtb, const f16* __restrict__ cqh,
    f16* __restrict__ Opart0, f16* __restrict__ Opart1,
    float* __restrict__ Lsum0, float* __restrict__ Lsum1)
{
  __shared__ f16 KVl[32768];    // 2 x (K 128x64 | V 64x128) = 64KB; epilogue alias
  __shared__ float Lsh[512];    // [w][64 q] row sums
  const int t = threadIdx.x, w = t >> 6, l = t & 63;
  const int r = l & 31, hi = l >> 5;
  const int ks = w >> 1, qh = w & 1;
  const int r7 = r & 7;
  // XCD-bijective swizzle: each XCD owns one (b,h)
  int nb2 = (blockIdx.x & 7) * 64 + (blockIdx.x >> 3);
  const int bh = nb2 >> 6, rest = nb2 & 63;
  const int qt = rest >> 1, kv = rest & 1;
  const int koff = kv * 2048;                     // key offset of this half
  f16* Opart = kv ? Opart1 : Opart0;
  float* Lsum = kv ? Lsum1 : Lsum0;
  const size_t base = (size_t)bh * NTOK * 64;
  // Q fragments: 2 sets x 4 chunks, scaled by combined per-d factor c
  f16x8 qf[2][4];
  {
    const f16* cp = cqh + bh * 64;
#pragma unroll
    for (int s = 0; s < 2; ++s) {
      const f16* qp = Qb + base + (size_t)(qt * 128 + qh * 64 + s * 32 + r) * 64 + hi * 8;
#pragma unroll
      for (int c = 0; c < 4; ++c)
        qf[s][c] = *(const f16x8*)(qp + c * 16) * *(const f16x8*)(cp + c * 16 + hi * 8);
    }
  }
  // staging source pointers (pre-swizzled global addresses, rule #21)
  const f16* srcK = Kb + base + (size_t)(koff + w * 8 + (l >> 3)) * 64 + ((l & 7) ^ (l >> 3)) * 8;
  const int vrow = w * 4 + (l >> 4);
  const f16* srcV = Vtb + base + (size_t)vrow * 4096 + koff + ((l & 15) ^ (vrow & 7)) * 8;
  const int dK = w * 512;
  const int dV = 8192 + w * 512;
#define STAGE(cur, tile) { \
    const f16* sk_ = srcK + (size_t)(tile) * 8192; \
    const f16* sv_ = srcV + (tile) * 128; \
    GLL(sk_,          KVl + (cur) * 16384 + dK); \
    GLL(sk_ + 4096,   KVl + (cur) * 16384 + dK + 4096); \
    GLL(sv_,          KVl + (cur) * 16384 + dV); \
    GLL(sv_ + 131072, KVl + (cur) * 16384 + dV + 4096); }
  // fragment read offsets (f16 units, constant across stages)
  const int kro = (ks * 32 + r) * 64;
  const int kc0 = ((0 + hi) ^ r7) * 8, kc1 = ((2 + hi) ^ r7) * 8;
  const int kc2 = ((4 + hi) ^ r7) * 8, kc3 = ((6 + hi) ^ r7) * 8;
  const int vb0 = 8192 + r * 128, vb1 = 8192 + (32 + r) * 128;
  const int vc0 = ((ks * 4 + 0 + hi) ^ r7) * 8, vc1 = ((ks * 4 + 2 + hi) ^ r7) * 8;

// per-set: QK -> in-register softmax -> PV  (all static indices)
#define SET_STEP(S, LSVAR) { \
    f32x16 sacc = {}; \
    __builtin_amdgcn_s_setprio(1); \
    sacc = __builtin_amdgcn_mfma_f32_32x32x16_f16(kf0, qf[S][0], sacc, 0, 0, 0); \
    sacc = __builtin_amdgcn_mfma_f32_32x32x16_f16(kf1, qf[S][1], sacc, 0, 0, 0); \
    sacc = __builtin_amdgcn_mfma_f32_32x32x16_f16(kf2, qf[S][2], sacc, 0, 0, 0); \
    sacc = __builtin_amdgcn_mfma_f32_32x32x16_f16(kf3, qf[S][3], sacc, 0, 0, 0); \
    __builtin_amdgcn_s_setprio(0); \
    u32 Dw[8]; \
    _Pragma("unroll") \
    for (int u = 0; u < 4; ++u) { \
      _Pragma("unroll") \
      for (int v = 0; v < 2; ++v) { \
        float a  = __builtin_amdgcn_exp2f(sacc[u * 4 + v * 2]); \
        float b2 = __builtin_amdgcn_exp2f(sacc[u * 4 + v * 2 + 1]); \
        LSVAR += a + b2; \
        union { fp16x2 h; u32 u; } cv; \
        cv.h = __builtin_amdgcn_cvt_pkrtz(a, b2); \
        Dw[u * 2 + v] = cv.u; \
      } \
    } \
    plane_swap(Dw[0], Dw[2]); \
    plane_swap(Dw[1], Dw[3]); \
    plane_swap(Dw[4], Dw[6]); \
    plane_swap(Dw[5], Dw[7]); \
    union { f16x8 v; u32 d[4]; } p0, p1; \
    p0.d[0] = Dw[0]; p0.d[1] = Dw[1]; p0.d[2] = Dw[2]; p0.d[3] = Dw[3]; \
    p1.d[0] = Dw[4]; p1.d[1] = Dw[5]; p1.d[2] = Dw[6]; p1.d[3] = Dw[7]; \
    __builtin_amdgcn_s_setprio(1); \
    oacc[S][0] = __builtin_amdgcn_mfma_f32_32x32x16_f16(p0.v, vf0, oacc[S][0], 0, 0, 0); \
    oacc[S][0] = __builtin_amdgcn_mfma_f32_32x32x16_f16(p1.v, vf1, oacc[S][0], 0, 0, 0); \
    oacc[S][1] = __builtin_amdgcn_mfma_f32_32x32x16_f16(p0.v, vf2, oacc[S][1], 0, 0, 0); \
    oacc[S][1] = __builtin_amdgcn_mfma_f32_32x32x16_f16(p1.v, vf3, oacc[S][1], 0, 0, 0); \
    __builtin_amdgcn_s_setprio(0); }

  f32x16 oacc[2][2] = {};
  float ls0 = 0.f, ls1 = 0.f;
  STAGE(0, 0);
  __syncthreads();
  for (int tl = 0; tl < 16; ++tl) {
    const int cur = tl & 1;
    const f16* Bb = KVl + cur * 16384;
    f16x8 kf0 = *(const f16x8*)(Bb + kro + kc0);
    f16x8 kf1 = *(const f16x8*)(Bb + kro + kc1);
    f16x8 kf2 = *(const f16x8*)(Bb + kro + kc2);
    f16x8 kf3 = *(const f16x8*)(Bb + kro + kc3);
    f16x8 vf0 = *(const f16x8*)(Bb + vb0 + vc0);
    f16x8 vf1 = *(const f16x8*)(Bb + vb0 + vc1);
    f16x8 vf2 = *(const f16x8*)(Bb + vb1 + vc0);
    f16x8 vf3 = *(const f16x8*)(Bb + vb1 + vc1);
    if (tl < 15) STAGE(cur ^ 1, tl + 1);
    SET_STEP(0, ls0);
    SET_STEP(1, ls1);
    __syncthreads();
  }
#undef STAGE
#undef SET_STEP
  // ---- epilogue: combine 4 key-slice partials via LDS; write global partials -
  ls0 += __shfl_xor(ls0, 32, 64);
  ls1 += __shfl_xor(ls1, 32, 64);
  if (hi == 0) { Lsh[w * 64 + r] = ls0; Lsh[w * 64 + 32 + r] = ls1; }
  // spill oacc as f16 into staging LDS: [w][dd 0..63][q-chunk^swz][8]
#pragma unroll
  for (int s = 0; s < 2; ++s)
#pragma unroll
    for (int dt = 0; dt < 2; ++dt) {
      f16* orow = KVl + w * 4096 + (dt * 32 + r) * 64;
      const f32x16& oa = oacc[s][dt];
#pragma unroll
      for (int u = 0; u < 4; ++u) {
        f16x4 h4;
        h4[0] = (f16)oa[u * 4 + 0]; h4[1] = (f16)oa[u * 4 + 1];
        h4[2] = (f16)oa[u * 4 + 2]; h4[3] = (f16)oa[u * 4 + 3];
        *(f16x4*)(orow + (((s * 4 + u) ^ r7) * 8) + hi * 4) = h4;
      }
    }
  __syncthreads();
  // combine region (s2, dt2, qh2) <- wave w; sum 4 key-slices; write partials
  const int s2 = w >> 2, dt2 = (w >> 1) & 1, qh2 = w & 1;
  const int blk = bh * 32 + qt;
#pragma unroll
  for (int c = 0; c < 2; ++c) {
    float accv[8] = {}, denv[8] = {};
#pragma unroll
    for (int ksl = 0; ksl < 4; ++ksl) {
      const int wp = ksl * 2 + qh2;
      f16x8 rd = *(const f16x8*)(KVl + wp * 4096 + (dt2 * 32 + r) * 64 +
                                 (((s2 * 4 + hi * 2 + c) ^ r7) * 8));
      f32x4 la = *(const f32x4*)(Lsh + wp * 64 + s2 * 32 + hi * 16 + c * 8);
      f32x4 lb = *(const f32x4*)(Lsh + wp * 64 + s2 * 32 + hi * 16 + c * 8 + 4);
#pragma unroll
      for (int j = 0; j < 4; ++j) {
        accv[j]     += (float)rd[j];
        accv[4 + j] += (float)rd[4 + j];
        denv[j]     += la[j];
        denv[4 + j] += lb[j];
      }
    }
    const int dd = dt2 * 32 + r;
    const int qloc = qh2 * 64 + (s2 * 4 + hi * 2 + c) * 8;   // q within 128-tile
    f16x8 ov;
#pragma unroll
    for (int j = 0; j < 8; ++j) ov[j] = (f16)accv[j];
    *(f16x8*)(Opart + (size_t)blk * 8192 + dd * 128 + qloc) = ov;
    if (dt2 == 0) {
      f32x4 d0, d1;
      d0[0] = denv[0]; d0[1] = denv[1]; d0[2] = denv[2]; d0[3] = denv[3];
      d1[0] = denv[4]; d1[1] = denv[5]; d1[2] = denv[6]; d1[3] = denv[7];
      *(f32x4*)(Lsum + blk * 128 + qloc) = d0;
      *(f32x4*)(Lsum + blk * 128 + qloc + 4) = d1;
    }
  }
}

// ---------------- merge kv halves: Y = (O0+O1)/(l0+l1), scrambled layout ------
__global__ __launch_bounds__(256) void k_comb(
    const f16* __restrict__ Opart0, const f16* __restrict__ Opart1,
    const float* __restrict__ Lsum0, const float* __restrict__ Lsum1,
    f16* __restrict__ Y)
{
  const int blk = blockIdx.x;           // bh*32 + qt
  const int bh = blk >> 5, qt = blk & 31;
  const int b = bh >> 2, h = bh & 3;
  const int t = threadIdx.x;
  const int dd = t >> 2, qc = t & 3;
#pragma unroll
  for (int j = 0; j < 4; ++j) {
    const int ql = qc * 32 + j * 8;
    f16x8 A = *(const f16x8*)(Opart0 + (size_t)blk * 8192 + dd * 128 + ql);
    f16x8 Bv = *(const f16x8*)(Opart1 + (size_t)blk * 8192 + dd * 128 + ql);
    f32x4 la0 = *(const f32x4*)(Lsum0 + blk * 128 + ql);
    f32x4 la1 = *(const f32x4*)(Lsum0 + blk * 128 + ql + 4);
    f32x4 lb0 = *(const f32x4*)(Lsum1 + blk * 128 + ql);
    f32x4 lb1 = *(const f32x4*)(Lsum1 + blk * 128 + ql + 4);
    const int ng = qt * 128 + ql;
    const int np = dd * 64 + h * 16 + (ng >> 8);
    const int cp = ng & 255;
    f16x8 yv;
#pragma unroll
    for (int jj = 0; jj < 4; ++jj) {
      yv[jj]     = (f16)(((float)A[jj]     + (float)Bv[jj])     / (la0[jj] + lb0[jj]));
      yv[4 + jj] = (f16)(((float)A[4 + jj] + (float)Bv[4 + jj]) / (la1[jj] + lb1[jj]));
    }
    *(f16x8*)(Y + ((size_t)b * 4096 + np) * 256 + cp) = yv;
  }
}

extern "C" void kernel_launch(void* const* d_in, const int* in_sizes, int n_in,
                              void* d_out, int out_size, void* d_ws, size_t ws_size,
                              hipStream_t stream)
{
  const float* x     = (const float*)d_in[0];   // [2,4096,256]
  const float* w_qkv = (const float*)d_in[1];   // [768,256]
  const float* w_out = (const float*)d_in[2];   // [256,256]
  const float* b_out = (const float*)d_in[3];   // [256]
  const float* temp  = (const float*)d_in[4];   // [4,1,1]

  char* ws = (char*)d_ws;
  // [0,4M):   xb (QKV gemm input) -> Opart0 (after QKV gemm; xb dead)
  // [4,4.5M): wqkvb -> Lsum0/Lsum1 (after QKV gemm)
  // [5,9M):   Qb -> Y (after flash7; Qb dead)
  // [9,13M):  Kb     [13,17M): Vtb
  // [17M..):  cqh, partQ, partK, woutb
  // [18,22M): Opart1
  f16*   xb     = (f16*)(ws);
  f16*   Opart0 = (f16*)(ws);
  f16*   wqkvb  = (f16*)(ws + 4 * 1024 * 1024);
  float* Lsum0  = (float*)(ws + 4 * 1024 * 1024);
  float* Lsum1  = (float*)(ws + 4 * 1024 * 1024 + 131072);
  f16*   Qb     = (f16*)(ws + 5  * 1024 * 1024);
  f16*   Y      = (f16*)(ws + 5  * 1024 * 1024);
  f16*   Kb     = (f16*)(ws + 9  * 1024 * 1024);
  f16*   Vtb    = (f16*)(ws + 13 * 1024 * 1024);
  f16*   cqh    = (f16*)(ws + 17 * 1024 * 1024);
  float* partQ  = (float*)(ws + 17 * 1024 * 1024 + 8192);
  float* partK  = (float*)(ws + 17 * 1024 * 1024 + 8192 + 131072);
  f16*   woutb  = (f16*)(ws + 17 * 1024 * 1024 + 512 * 1024);
  f16*   Opart1 = (f16*)(ws + 18 * 1024 * 1024);
  float* outF   = (float*)d_out;

  k_cvt<<<2304, 256, 0, stream>>>(x, w_qkv, w_out, xb, wqkvb, woutb);
  k_gemm<<<dim3(12, 128), 256, 0, stream>>>(xb, wqkvb, 256, 0, Qb, Kb, Vtb,
                                            nullptr, nullptr, partQ, partK);
  k_norm2<<<1, 512, 0, stream>>>(partQ, partK, temp, cqh);
  k_flash7<<<512, 512, 0, stream>>>(Qb, Kb, Vtb, cqh, Opart0, Opart1, Lsum0, Lsum1);
  k_comb<<<256, 256, 0, stream>>>(Opart0, Opart1, Lsum0, Lsum1, Y);
  k_gemm<<<dim3(4, 128), 256, 0, stream>>>(Y, woutb, 256, 1, nullptr, nullptr, nullptr,
                                           outF, b_out, nullptr, nullptr);
}

// Round 11
// 109.265 us; speedup vs baseline: 3.1129x; 3.1129x over previous
//
#include <hip/hip_runtime.h>

typedef _Float16 f16;
typedef f16 f16x8 __attribute__((ext_vector_type(8)));
typedef f16 f16x4 __attribute__((ext_vector_type(4)));
typedef __fp16 fp16x2 __attribute__((ext_vector_type(2)));
typedef float f32x4 __attribute__((ext_vector_type(4)));
typedef float f32x16 __attribute__((ext_vector_type(16)));
typedef unsigned int u32;

#define NTOK 4096

// async global->LDS, 16B per lane; dest = wave-uniform base + lane*16
#define GLL(gsrc, ldst) \
  __builtin_amdgcn_global_load_lds( \
      (const __attribute__((address_space(1))) void*)(gsrc), \
      (__attribute__((address_space(3))) void*)(ldst), 16, 0, 0)

// ---------------- f32 -> f16 convert (weights only: w_qkv | w_out) ------------
__global__ __launch_bounds__(256) void k_cvt(
    const float* __restrict__ wq, const float* __restrict__ wo,
    f16* __restrict__ wqb, f16* __restrict__ wob)
{
  const int bx = blockIdx.x;
  const float* src; f16* dst; int off;
  if (bx < 192) { src = wq; dst = wqb; off = bx * 1024; }
  else          { src = wo; dst = wob; off = (bx - 192) * 1024; }
  const int i = off + threadIdx.x * 4;
  float4 f = *(const float4*)(src + i);
  f16x4 h;
  h[0] = (f16)f.x; h[1] = (f16)f.y; h[2] = (f16)f.z; h[3] = (f16)f.w;
  *(f16x4*)(dst + i) = h;
}

// ---------------- generic C = A[M,K] * W[NC,K]^T MFMA GEMM ----------------
// mode 0: A = x (f32, converted inline) -> scatter Qb/Kb/Vtb + norm partials
// mode 1: A = Y (f16) -> d_out f32 + bias
__global__ __launch_bounds__(256) void k_gemm(
    const void* __restrict__ Araw, const f16* __restrict__ W,
    int K, int mode,
    f16* __restrict__ Qb, f16* __restrict__ Kb, f16* __restrict__ Vtb,
    float* __restrict__ outF, const float* __restrict__ bias,
    float* __restrict__ partQ, float* __restrict__ partK)
{
  __shared__ f16 Al[64 * 40];
  __shared__ f16 Wl[64 * 40];
  __shared__ float redl[4][64];
  const int t = threadIdx.x;
  const int w = t >> 6, l = t & 63;
  const int lrow = l & 15, lk = l >> 4;
  const int m0 = blockIdx.y * 64, nc0 = blockIdx.x * 64;
  f32x4 acc[4] = {};
  const int srow = t >> 2, sseg = t & 3;
  for (int k0 = 0; k0 < K; k0 += 32) {
    __syncthreads();
    f16x8 av;
    if (mode == 0) {
      const float* ap = (const float*)Araw + (size_t)(m0 + srow) * K + k0 + sseg * 8;
      float4 a0 = *(const float4*)(ap);
      float4 a1 = *(const float4*)(ap + 4);
      av[0] = (f16)a0.x; av[1] = (f16)a0.y; av[2] = (f16)a0.z; av[3] = (f16)a0.w;
      av[4] = (f16)a1.x; av[5] = (f16)a1.y; av[6] = (f16)a1.z; av[7] = (f16)a1.w;
    } else {
      av = *(const f16x8*)((const f16*)Araw + (size_t)(m0 + srow) * K + k0 + sseg * 8);
    }
    f16x8 wv = *(const f16x8*)(W + (size_t)(nc0 + srow) * K + k0 + sseg * 8);
    *(f16x8*)(Al + srow * 40 + sseg * 8) = av;
    *(f16x8*)(Wl + srow * 40 + sseg * 8) = wv;
    __syncthreads();
    f16x8 af = *(const f16x8*)(Al + (w * 16 + lrow) * 40 + lk * 8);
#pragma unroll
    for (int ct = 0; ct < 4; ++ct) {
      f16x8 bf = *(const f16x8*)(Wl + (ct * 16 + lrow) * 40 + lk * 8);
      acc[ct] = __builtin_amdgcn_mfma_f32_16x16x32_f16(af, bf, acc[ct], 0, 0, 0);
    }
  }
  const int nb = m0 + w * 16 + lk * 4;
  if (mode == 0) {
    const int b = nb >> 12, n = nb & 4095;
#pragma unroll
    for (int ct = 0; ct < 4; ++ct) {
      int gc = nc0 + ct * 16 + lrow;
      int s = gc >> 8, h = (gc >> 6) & 3, dd = gc & 63;
      int bh = b * 4 + h;
      if (s == 2) {
        f16x4 v;
#pragma unroll
        for (int j = 0; j < 4; ++j) v[j] = (f16)acc[ct][j];
        *(f16x4*)(Vtb + ((size_t)bh * 64 + dd) * 4096 + n) = v;
      } else {
        f16* dst = (s == 0) ? Qb : Kb;
#pragma unroll
        for (int j = 0; j < 4; ++j)
          dst[((size_t)bh * 4096 + n + j) * 64 + dd] = (f16)acc[ct][j];
      }
    }
    // fused per-channel squared-sum partials (over this block's 64 tokens)
    if (nc0 < 512) {
#pragma unroll
      for (int ct = 0; ct < 4; ++ct) {
        float v = acc[ct][0] * acc[ct][0] + acc[ct][1] * acc[ct][1]
                + acc[ct][2] * acc[ct][2] + acc[ct][3] * acc[ct][3];
        v += __shfl_xor(v, 16, 64);
        v += __shfl_xor(v, 32, 64);
        if (lk == 0) redl[w][ct * 16 + lrow] = v;
      }
      __syncthreads();
      if (t < 64) {
        float sq = redl[0][t] + redl[1][t] + redl[2][t] + redl[3][t];
        const int s = nc0 >> 8, h2 = (nc0 >> 6) & 3;
        const int b2 = m0 >> 12, mb = (m0 >> 6) & 63;
        float* dst = (s == 0) ? partQ : partK;
        dst[((b2 * 4 + h2) * 64 + mb) * 64 + t] = sq;
      }
    }
  } else {
#pragma unroll
    for (int ct = 0; ct < 4; ++ct) {
      int gc = nc0 + ct * 16 + lrow;
      float bv = bias[gc];
#pragma unroll
      for (int j = 0; j < 4; ++j)
        outF[(size_t)(nb + j) * 256 + gc] = acc[ct][j] + bv;
    }
  }
}

// ---------------- finalize: combined Q-side scale c = temp*log2e/(|q||k|) ----
__global__ __launch_bounds__(512) void k_norm2(
    const float* __restrict__ partQ, const float* __restrict__ partK,
    const float* __restrict__ temp, f16* __restrict__ cqh)
{
  const int t = threadIdx.x;            // 512 = 8 bh * 64 dd
  const int bh = t >> 6, dd = t & 63;
  float sq = 0.f, sk = 0.f;
  for (int s = 0; s < 64; ++s) {
    sq += partQ[(bh * 64 + s) * 64 + dd];
    sk += partK[(bh * 64 + s) * 64 + dd];
  }
  float c = temp[bh & 3] * 1.4426950408889634f /
            (fmaxf(sqrtf(sq), 1e-12f) * fmaxf(sqrtf(sk), 1e-12f));
  cqh[t] = (f16)c;
}

// ---------------- flash attention v8: flash6 + V direct from global (L1) -----
// QBLK=64, 512 blocks, 2 blocks/CU, 8 waves = 4 ks x 2 qh.  K LDS-staged via
// GLL dbuf (2 x 16KB); V B-frags read straight from Vtb (16B/lane, L1-resident
// per tile, no barrier dependency).  In-register softmax (T12).
__device__ inline void plane_swap(u32& a, u32& b) {
  asm volatile("v_permlane32_swap_b32 %0, %1" : "+v"(a), "+v"(b));
}

__global__ __launch_bounds__(512, 4) void k_flash8(
    const f16* __restrict__ Qb, const f16* __restrict__ Kb,
    const f16* __restrict__ Vtb, const f16* __restrict__ cqh,
    f16* __restrict__ Y)
{
  __shared__ f16 KVl[16384];    // 2 x K[128 keys][64 d] dbuf; epilogue alias
  __shared__ float Lsh[256];    // [w][32 q] row sums
  const int t = threadIdx.x, w = t >> 6, l = t & 63;
  const int r = l & 31, hi = l >> 5;
  const int ks = w >> 1, qh = w & 1;
  const int r7 = r & 7;
  // XCD-bijective swizzle: 512 blocks, each XCD owns one (b,h)
  int nb2 = (blockIdx.x & 7) * 64 + (blockIdx.x >> 3);
  const int bh = nb2 >> 6, qt = nb2 & 63;
  const size_t base = (size_t)bh * NTOK * 64;
  // Q fragments (32 q), scaled by combined per-d factor c
  f16x8 qf0, qf1, qf2, qf3;
  {
    const f16* cq = cqh + bh * 64;
    const f16* qp = Qb + base + (size_t)(qt * 64 + qh * 32 + r) * 64 + hi * 8;
    qf0 = *(const f16x8*)(qp)      * *(const f16x8*)(cq +  0 + hi * 8);
    qf1 = *(const f16x8*)(qp + 16) * *(const f16x8*)(cq + 16 + hi * 8);
    qf2 = *(const f16x8*)(qp + 32) * *(const f16x8*)(cq + 32 + hi * 8);
    qf3 = *(const f16x8*)(qp + 48) * *(const f16x8*)(cq + 48 + hi * 8);
  }
  // K staging source (pre-swizzled global, rule #21): 2 GLLs/wave/tile
  const f16* srcK = Kb + base + (size_t)(w * 8 + (l >> 3)) * 64 + ((l & 7) ^ (l >> 3)) * 8;
  const int dK = w * 512;
#define STAGE(cur, tile) { \
    const f16* sk_ = srcK + (size_t)(tile) * 8192; \
    GLL(sk_,        KVl + (cur) * 8192 + dK); \
    GLL(sk_ + 4096, KVl + (cur) * 8192 + dK + 4096); }
  // K fragment read offsets (f16 units, XOR-swizzled)
  const int kro = (ks * 32 + r) * 64;
  const int kc0 = ((0 + hi) ^ r7) * 8, kc1 = ((2 + hi) ^ r7) * 8;
  const int kc2 = ((4 + hi) ^ r7) * 8, kc3 = ((6 + hi) ^ r7) * 8;
  // V direct-global base: lane reads rows dd=r and dd=32+r, chunks ks*4+{0,2}+hi
  const f16* vp = Vtb + base + (size_t)r * 4096 + (ks * 4 + hi) * 8;

  f32x16 oacc0 = {}, oacc1 = {};
  float lsw = 0.f;
  STAGE(0, 0);
  __syncthreads();
  for (int tl = 0; tl < 32; ++tl) {
    const int cur = tl & 1;
    // V loads first: no dependency, latency hides under QK+softmax
    const f16* vt = vp + tl * 128;
    f16x8 vf0 = *(const f16x8*)(vt);
    f16x8 vf1 = *(const f16x8*)(vt + 16);
    f16x8 vf2 = *(const f16x8*)(vt + 32 * 4096);
    f16x8 vf3 = *(const f16x8*)(vt + 32 * 4096 + 16);
    const f16* Bb = KVl + cur * 8192;
    f16x8 kf0 = *(const f16x8*)(Bb + kro + kc0);
    f16x8 kf1 = *(const f16x8*)(Bb + kro + kc1);
    f16x8 kf2 = *(const f16x8*)(Bb + kro + kc2);
    f16x8 kf3 = *(const f16x8*)(Bb + kro + kc3);
    if (tl < 31) STAGE(cur ^ 1, tl + 1);
    // QK^T
    f32x16 sacc = {};
    __builtin_amdgcn_s_setprio(1);
    sacc = __builtin_amdgcn_mfma_f32_32x32x16_f16(kf0, qf0, sacc, 0, 0, 0);
    sacc = __builtin_amdgcn_mfma_f32_32x32x16_f16(kf1, qf1, sacc, 0, 0, 0);
    sacc = __builtin_amdgcn_mfma_f32_32x32x16_f16(kf2, qf2, sacc, 0, 0, 0);
    sacc = __builtin_amdgcn_mfma_f32_32x32x16_f16(kf3, qf3, sacc, 0, 0, 0);
    __builtin_amdgcn_s_setprio(0);
    // softmax in-register: exp2, pack, permlane redistribute
    u32 Dw[8];
#pragma unroll
    for (int u = 0; u < 4; ++u) {
#pragma unroll
      for (int v = 0; v < 2; ++v) {
        float a  = __builtin_amdgcn_exp2f(sacc[u * 4 + v * 2]);
        float b2 = __builtin_amdgcn_exp2f(sacc[u * 4 + v * 2 + 1]);
        lsw += a + b2;
        union { fp16x2 h; u32 u; } cv;
        cv.h = __builtin_amdgcn_cvt_pkrtz(a, b2);
        Dw[u * 2 + v] = cv.u;
      }
    }
    plane_swap(Dw[0], Dw[2]);
    plane_swap(Dw[1], Dw[3]);
    plane_swap(Dw[4], Dw[6]);
    plane_swap(Dw[5], Dw[7]);
    union { f16x8 v; u32 d[4]; } p0, p1;
    p0.d[0] = Dw[0]; p0.d[1] = Dw[1]; p0.d[2] = Dw[2]; p0.d[3] = Dw[3];
    p1.d[0] = Dw[4]; p1.d[1] = Dw[5]; p1.d[2] = Dw[6]; p1.d[3] = Dw[7];
    // PV (V from registers, loaded direct from global)
    __builtin_amdgcn_s_setprio(1);
    oacc0 = __builtin_amdgcn_mfma_f32_32x32x16_f16(p0.v, vf0, oacc0, 0, 0, 0);
    oacc0 = __builtin_amdgcn_mfma_f32_32x32x16_f16(p1.v, vf1, oacc0, 0, 0, 0);
    oacc1 = __builtin_amdgcn_mfma_f32_32x32x16_f16(p0.v, vf2, oacc1, 0, 0, 0);
    oacc1 = __builtin_amdgcn_mfma_f32_32x32x16_f16(p1.v, vf3, oacc1, 0, 0, 0);
    __builtin_amdgcn_s_setprio(0);
    __syncthreads();
  }
#undef STAGE
  // ---- epilogue: combine 4 key-slice partials via LDS (alias of KVl) ----
  lsw += __shfl_xor(lsw, 32, 64);
  if (hi == 0) Lsh[w * 32 + r] = lsw;
#pragma unroll
  for (int dt = 0; dt < 2; ++dt) {
    f16* orow = KVl + w * 2048 + (dt * 32 + r) * 32;
    const f32x16& oa = dt ? oacc1 : oacc0;
#pragma unroll
    for (int u = 0; u < 4; ++u) {
      f16x4 h4;
      h4[0] = (f16)oa[u * 4 + 0]; h4[1] = (f16)oa[u * 4 + 1];
      h4[2] = (f16)oa[u * 4 + 2]; h4[3] = (f16)oa[u * 4 + 3];
      *(f16x4*)(orow + ((u ^ (r & 3)) * 8) + hi * 4) = h4;
    }
  }
  __syncthreads();
  // combine: wave w = (s2 q-16-group-pair, dt2 dd-half, qh2 q-half)
  const int s2 = w >> 2, dt2 = (w >> 1) & 1, qh2 = w & 1;
  const int g = s2 * 2 + hi;    // q 8-group within 32-half
  const int b = bh >> 2, h = bh & 3;
  float accv[8] = {}, denv[8] = {};
#pragma unroll
  for (int ksl = 0; ksl < 4; ++ksl) {
    const int wp = ksl * 2 + qh2;
    f16x8 rd = *(const f16x8*)(KVl + wp * 2048 + (dt2 * 32 + r) * 32 + ((g ^ (r & 3)) * 8));
    f32x4 la = *(const f32x4*)(Lsh + wp * 32 + g * 8);
    f32x4 lb = *(const f32x4*)(Lsh + wp * 32 + g * 8 + 4);
#pragma unroll
    for (int j = 0; j < 4; ++j) {
      accv[j]     += (float)rd[j];
      accv[4 + j] += (float)rd[4 + j];
      denv[j]     += la[j];
      denv[4 + j] += lb[j];
    }
  }
  const int ng = qt * 64 + qh2 * 32 + g * 8;
  const int np = (dt2 * 32 + r) * 64 + h * 16 + (ng >> 8);
  const int cp_ = ng & 255;
  f16x8 yv;
#pragma unroll
  for (int j = 0; j < 8; ++j) yv[j] = (f16)(accv[j] / denv[j]);
  *(f16x8*)(Y + ((size_t)b * 4096 + np) * 256 + cp_) = yv;
}

extern "C" void kernel_launch(void* const* d_in, const int* in_sizes, int n_in,
                              void* d_out, int out_size, void* d_ws, size_t ws_size,
                              hipStream_t stream)
{
  const float* x     = (const float*)d_in[0];   // [2,4096,256]
  const float* w_qkv = (const float*)d_in[1];   // [768,256]
  const float* w_out = (const float*)d_in[2];   // [256,256]
  const float* b_out = (const float*)d_in[3];   // [256]
  const float* temp  = (const float*)d_in[4];   // [4,1,1]

  char* ws = (char*)d_ws;
  f16*   wqkvb = (f16*)(ws + 4 * 1024 * 1024);
  f16*   woutb = (f16*)(ws + 4 * 1024 * 1024 + 512 * 1024);
  f16*   Qb    = (f16*)(ws + 5  * 1024 * 1024);               // [8][4096][64]
  f16*   Kb    = (f16*)(ws + 9  * 1024 * 1024);
  f16*   Vtb   = (f16*)(ws + 13 * 1024 * 1024);               // [8][64][4096]
  f16*   cqh   = (f16*)(ws + 17 * 1024 * 1024);               // 512 f16
  float* partQ = (float*)(ws + 17 * 1024 * 1024 + 8192);      // 128KB
  float* partK = (float*)(ws + 17 * 1024 * 1024 + 8192 + 131072);
  f16*   Y     = (f16*)(ws + 18 * 1024 * 1024);               // [2][4096][256]
  float* outF  = (float*)d_out;

  k_cvt<<<256, 256, 0, stream>>>(w_qkv, w_out, wqkvb, woutb);
  k_gemm<<<dim3(12, 128), 256, 0, stream>>>(x, wqkvb, 256, 0, Qb, Kb, Vtb,
                                            nullptr, nullptr, partQ, partK);
  k_norm2<<<1, 512, 0, stream>>>(partQ, partK, temp, cqh);
  k_flash8<<<512, 512, 0, stream>>>(Qb, Kb, Vtb, cqh, Y);
  k_gemm<<<dim3(4, 128), 256, 0, stream>>>(Y, woutb, 256, 1, nullptr, nullptr, nullptr,
                                           outF, b_out, nullptr, nullptr);
}

// Round 13
// 98.765 us; speedup vs baseline: 3.4439x; 1.1063x over previous
//
#include <hip/hip_runtime.h>

typedef _Float16 f16;
typedef f16 f16x8 __attribute__((ext_vector_type(8)));
typedef f16 f16x4 __attribute__((ext_vector_type(4)));
typedef __fp16 fp16x2 __attribute__((ext_vector_type(2)));
typedef float f32x4 __attribute__((ext_vector_type(4)));
typedef float f32x16 __attribute__((ext_vector_type(16)));
typedef unsigned int u32;

#define NTOK 4096

// async global->LDS, 16B per lane; dest MUST be wave-uniform (HW: base + lane*16)
#define GLL(gsrc, ldst) \
  __builtin_amdgcn_global_load_lds( \
      (const __attribute__((address_space(1))) void*)(gsrc), \
      (__attribute__((address_space(3))) void*)(ldst), 16, 0, 0)

// ---------------- f32 -> f16 convert (weights only: w_qkv | w_out) ------------
__global__ __launch_bounds__(256) void k_cvt(
    const float* __restrict__ wq, const float* __restrict__ wo,
    f16* __restrict__ wqb, f16* __restrict__ wob)
{
  const int bx = blockIdx.x;
  const float* src; f16* dst; int off;
  if (bx < 192) { src = wq; dst = wqb; off = bx * 1024; }
  else          { src = wo; dst = wob; off = (bx - 192) * 1024; }
  const int i = off + threadIdx.x * 4;
  float4 f = *(const float4*)(src + i);
  f16x4 h;
  h[0] = (f16)f.x; h[1] = (f16)f.y; h[2] = (f16)f.z; h[3] = (f16)f.w;
  *(f16x4*)(dst + i) = h;
}

// ---------------- QKV GEMM: 128x128 tile, inline f32->f16, fused norm partials
// grid (6, 64): nc0 = bx*128 (768 qkv channels), m0 = by*128 (8192 tokens).
// 4 waves in 2x2 quadrants of 64x64; acc[4][4] f32x4; W staged via GLL with
// WAVE-UNIFORM LDS dest (lane l lands at base + l*16B -> row w*32+(l>>2),
// chunk l&3) and per-lane pre-swizzled global source (rule #21).
__global__ __launch_bounds__(256, 2) void k_qkv(
    const float* __restrict__ x, const f16* __restrict__ W,
    f16* __restrict__ Qb, f16* __restrict__ Kb, f16* __restrict__ Vtb,
    float* __restrict__ partQ, float* __restrict__ partK)
{
  __shared__ f16 Al[128 * 40];     // [row][32 k + 8 pad]
  __shared__ f16 Wl[128 * 32];     // linear rows of 64B, XOR-swizzled 16B chunks
  __shared__ float redl[4][64];
  const int t = threadIdx.x;
  const int w = t >> 6, l = t & 63;
  const int lrow = l & 15, lk = l >> 4;
  const int wm = w >> 1, wn = w & 1;
  const int m0 = blockIdx.y * 128, nc0 = blockIdx.x * 128;
  // A staging: thread covers row ar, 16-f32 segment aseg
  const int ar = t >> 1, aseg = t & 1;
  const float* asrc = x + (size_t)(m0 + ar) * 256 + aseg * 16;
  f16* adst = Al + ar * 40 + aseg * 16;
  // W staging: per-lane global source (pre-swizzled), wave-uniform LDS dest
  const int wrow = w * 32 + (l >> 2), wc = l & 3;
  const f16* srcW1 = W + (size_t)(nc0 + wrow) * 256 + ((wc ^ (wrow & 3)) * 8);
  const f16* srcW2 = W + (size_t)(nc0 + wrow + 16) * 256 + ((wc ^ (wrow & 3)) * 8);
  f16* dstW1 = Wl + w * 1024;        // wave-uniform base (rows w*32..w*32+15)
  f16* dstW2 = Wl + w * 1024 + 512;  // rows w*32+16..w*32+31
  f32x4 acc[4][4] = {};
  for (int k0 = 0; k0 < 256; k0 += 32) {
    __syncthreads();
    GLL(srcW1 + k0, dstW1);
    GLL(srcW2 + k0, dstW2);
    {
      const float* ap = asrc + k0;
      float4 a0 = *(const float4*)(ap);
      float4 a1 = *(const float4*)(ap + 4);
      float4 a2 = *(const float4*)(ap + 8);
      float4 a3 = *(const float4*)(ap + 12);
      f16x8 h0, h1;
      h0[0] = (f16)a0.x; h0[1] = (f16)a0.y; h0[2] = (f16)a0.z; h0[3] = (f16)a0.w;
      h0[4] = (f16)a1.x; h0[5] = (f16)a1.y; h0[6] = (f16)a1.z; h0[7] = (f16)a1.w;
      h1[0] = (f16)a2.x; h1[1] = (f16)a2.y; h1[2] = (f16)a2.z; h1[3] = (f16)a2.w;
      h1[4] = (f16)a3.x; h1[5] = (f16)a3.y; h1[6] = (f16)a3.z; h1[7] = (f16)a3.w;
      *(f16x8*)(adst) = h0;
      *(f16x8*)(adst + 8) = h1;
    }
    __syncthreads();
    f16x8 wf[4];
#pragma unroll
    for (int fc = 0; fc < 4; ++fc) {
      const int row = wn * 64 + fc * 16 + lrow;
      wf[fc] = *(const f16x8*)(Wl + row * 32 + ((lk ^ (row & 3)) * 8));
    }
#pragma unroll
    for (int fr = 0; fr < 4; ++fr) {
      f16x8 af = *(const f16x8*)(Al + (wm * 64 + fr * 16 + lrow) * 40 + lk * 8);
#pragma unroll
      for (int fc = 0; fc < 4; ++fc)
        acc[fr][fc] = __builtin_amdgcn_mfma_f32_16x16x32_f16(af, wf[fc], acc[fr][fc], 0, 0, 0);
    }
  }
  // ---- epilogue: scatter Q/K/V ----
  const int b = m0 >> 12, nbb = m0 & 4095;
#pragma unroll
  for (int fc = 0; fc < 4; ++fc) {
    const int gc = nc0 + wn * 64 + fc * 16 + lrow;
    const int s = gc >> 8, h = (gc >> 6) & 3, dd = gc & 63;
    const int bh = b * 4 + h;
#pragma unroll
    for (int fr = 0; fr < 4; ++fr) {
      const int n = nbb + wm * 64 + fr * 16 + lk * 4;
      if (s == 2) {
        f16x4 v;
#pragma unroll
        for (int j = 0; j < 4; ++j) v[j] = (f16)acc[fr][fc][j];
        *(f16x4*)(Vtb + ((size_t)bh * 64 + dd) * 4096 + n) = v;
      } else {
        f16* dst = (s == 0) ? Qb : Kb;
#pragma unroll
        for (int j = 0; j < 4; ++j)
          dst[((size_t)bh * 4096 + n + j) * 64 + dd] = (f16)acc[fr][fc][j];
      }
    }
  }
  // ---- fused per-channel squared-sum partials over this block's 128 tokens ----
  if (nc0 < 512) {
    float vsum[4] = {};
#pragma unroll
    for (int fc = 0; fc < 4; ++fc) {
#pragma unroll
      for (int fr = 0; fr < 4; ++fr) {
        float v = acc[fr][fc][0] * acc[fr][fc][0] + acc[fr][fc][1] * acc[fr][fc][1]
                + acc[fr][fc][2] * acc[fr][fc][2] + acc[fr][fc][3] * acc[fr][fc][3];
        vsum[fc] += v;
      }
      vsum[fc] += __shfl_xor(vsum[fc], 16, 64);
      vsum[fc] += __shfl_xor(vsum[fc], 32, 64);
    }
    __syncthreads();
    if (lk == 0) {
#pragma unroll
      for (int fc = 0; fc < 4; ++fc) redl[w][fc * 16 + lrow] = vsum[fc];
    }
    __syncthreads();
    if (t < 128) {
      const int wn2 = t >> 6, dd = t & 63;
      const float sq = redl[wn2][dd] + redl[2 + wn2][dd];
      const int h = ((nc0 >> 6) & 3) + wn2;
      const int mb = (m0 >> 7) & 31;
      float* dst = (nc0 >> 8) == 0 ? partQ : partK;
      dst[((b * 4 + h) * 32 + mb) * 64 + dd] = sq;
    }
  }
}

// ---------------- finalize: combined Q-side scale c = temp*log2e/(|q||k|) ----
__global__ __launch_bounds__(512) void k_norm2(
    const float* __restrict__ partQ, const float* __restrict__ partK,
    const float* __restrict__ temp, f16* __restrict__ cqh)
{
  const int t = threadIdx.x;            // 512 = 8 bh * 64 dd
  const int bh = t >> 6, dd = t & 63;
  float sq = 0.f, sk = 0.f;
  for (int s = 0; s < 32; ++s) {
    sq += partQ[(bh * 32 + s) * 64 + dd];
    sk += partK[(bh * 32 + s) * 64 + dd];
  }
  float c = temp[bh & 3] * 1.4426950408889634f /
            (fmaxf(sqrtf(sq), 1e-12f) * fmaxf(sqrtf(sk), 1e-12f));
  cqh[t] = (f16)c;
}

// ---------------- flash attention v6 (round-9 exact order, proven) -----------
// QBLK=64, 512 blocks, 2 blocks/CU, 8 waves = 4 ks x 2 qh; K,V LDS dbuf via GLL.
__device__ inline void plane_swap(u32& a, u32& b) {
  asm volatile("v_permlane32_swap_b32 %0, %1" : "+v"(a), "+v"(b));
}

__global__ __launch_bounds__(512, 4) void k_flash6(
    const f16* __restrict__ Qb, const f16* __restrict__ Kb,
    const f16* __restrict__ Vtb, const f16* __restrict__ cqh,
    f16* __restrict__ Y)
{
  __shared__ f16 KVl[32768];    // 2 x (K 128x64 | V 64x128) = 64KB; epilogue alias
  __shared__ float Lsh[256];    // [w][32 q] row sums
  const int t = threadIdx.x, w = t >> 6, l = t & 63;
  const int r = l & 31, hi = l >> 5;
  const int ks = w >> 1, qh = w & 1;
  const int r7 = r & 7;
  // XCD-bijective swizzle: 512 blocks, each XCD owns one (b,h)
  int nb2 = (blockIdx.x & 7) * 64 + (blockIdx.x >> 3);
  const int bh = nb2 >> 6, qt = nb2 & 63;
  const size_t base = (size_t)bh * NTOK * 64;
  // Q fragments (32 q), scaled by combined per-d factor c
  f16x8 qf0, qf1, qf2, qf3;
  {
    const f16* cq = cqh + bh * 64;
    const f16* qp = Qb + base + (size_t)(qt * 64 + qh * 32 + r) * 64 + hi * 8;
    qf0 = *(const f16x8*)(qp)      * *(const f16x8*)(cq +  0 + hi * 8);
    qf1 = *(const f16x8*)(qp + 16) * *(const f16x8*)(cq + 16 + hi * 8);
    qf2 = *(const f16x8*)(qp + 32) * *(const f16x8*)(cq + 32 + hi * 8);
    qf3 = *(const f16x8*)(qp + 48) * *(const f16x8*)(cq + 48 + hi * 8);
  }
  // staging source pointers (pre-swizzled global addresses, rule #21)
  const f16* srcK = Kb + base + (size_t)(w * 8 + (l >> 3)) * 64 + ((l & 7) ^ (l >> 3)) * 8;
  const int vrow = w * 4 + (l >> 4);
  const f16* srcV = Vtb + base + (size_t)vrow * 4096 + ((l & 15) ^ (vrow & 7)) * 8;
  const int dK = w * 512;
  const int dV = 8192 + w * 512;
#define STAGE(cur, tile) { \
    const f16* sk_ = srcK + (size_t)(tile) * 8192; \
    const f16* sv_ = srcV + (tile) * 128; \
    GLL(sk_,          KVl + (cur) * 16384 + dK); \
    GLL(sk_ + 4096,   KVl + (cur) * 16384 + dK + 4096); \
    GLL(sv_,          KVl + (cur) * 16384 + dV); \
    GLL(sv_ + 131072, KVl + (cur) * 16384 + dV + 4096); }
  // fragment read offsets (f16 units, constant across stages)
  const int kro = (ks * 32 + r) * 64;
  const int kc0 = ((0 + hi) ^ r7) * 8, kc1 = ((2 + hi) ^ r7) * 8;
  const int kc2 = ((4 + hi) ^ r7) * 8, kc3 = ((6 + hi) ^ r7) * 8;
  const int vb0 = 8192 + r * 128, vb1 = 8192 + (32 + r) * 128;
  const int vc0 = ((ks * 4 + 0 + hi) ^ r7) * 8, vc1 = ((ks * 4 + 2 + hi) ^ r7) * 8;

  f32x16 oacc0 = {}, oacc1 = {};
  float lsw = 0.f;
  STAGE(0, 0);
  __syncthreads();
  for (int tl = 0; tl < 32; ++tl) {
    const int cur = tl & 1;
    const f16* Bb = KVl + cur * 16384;
    f16x8 kf0 = *(const f16x8*)(Bb + kro + kc0);
    f16x8 kf1 = *(const f16x8*)(Bb + kro + kc1);
    f16x8 kf2 = *(const f16x8*)(Bb + kro + kc2);
    f16x8 kf3 = *(const f16x8*)(Bb + kro + kc3);
    f16x8 vf0 = *(const f16x8*)(Bb + vb0 + vc0);
    f16x8 vf1 = *(const f16x8*)(Bb + vb0 + vc1);
    f16x8 vf2 = *(const f16x8*)(Bb + vb1 + vc0);
    f16x8 vf3 = *(const f16x8*)(Bb + vb1 + vc1);
    if (tl < 31) STAGE(cur ^ 1, tl + 1);
    // QK^T
    f32x16 sacc = {};
    __builtin_amdgcn_s_setprio(1);
    sacc = __builtin_amdgcn_mfma_f32_32x32x16_f16(kf0, qf0, sacc, 0, 0, 0);
    sacc = __builtin_amdgcn_mfma_f32_32x32x16_f16(kf1, qf1, sacc, 0, 0, 0);
    sacc = __builtin_amdgcn_mfma_f32_32x32x16_f16(kf2, qf2, sacc, 0, 0, 0);
    sacc = __builtin_amdgcn_mfma_f32_32x32x16_f16(kf3, qf3, sacc, 0, 0, 0);
    __builtin_amdgcn_s_setprio(0);
    // softmax in-register: exp2, pack, permlane redistribute
    u32 Dw[8];
#pragma unroll
    for (int u = 0; u < 4; ++u) {
#pragma unroll
      for (int v = 0; v < 2; ++v) {
        float a  = __builtin_amdgcn_exp2f(sacc[u * 4 + v * 2]);
        float b2 = __builtin_amdgcn_exp2f(sacc[u * 4 + v * 2 + 1]);
        lsw += a + b2;
        union { fp16x2 h; u32 u; } cv;
        cv.h = __builtin_amdgcn_cvt_pkrtz(a, b2);
        Dw[u * 2 + v] = cv.u;
      }
    }
    plane_swap(Dw[0], Dw[2]);
    plane_swap(Dw[1], Dw[3]);
    plane_swap(Dw[4], Dw[6]);
    plane_swap(Dw[5], Dw[7]);
    union { f16x8 v; u32 d[4]; } p0, p1;
    p0.d[0] = Dw[0]; p0.d[1] = Dw[1]; p0.d[2] = Dw[2]; p0.d[3] = Dw[3];
    p1.d[0] = Dw[4]; p1.d[1] = Dw[5]; p1.d[2] = Dw[6]; p1.d[3] = Dw[7];
    // PV
    __builtin_amdgcn_s_setprio(1);
    oacc0 = __builtin_amdgcn_mfma_f32_32x32x16_f16(p0.v, vf0, oacc0, 0, 0, 0);
    oacc0 = __builtin_amdgcn_mfma_f32_32x32x16_f16(p1.v, vf1, oacc0, 0, 0, 0);
    oacc1 = __builtin_amdgcn_mfma_f32_32x32x16_f16(p0.v, vf2, oacc1, 0, 0, 0);
    oacc1 = __builtin_amdgcn_mfma_f32_32x32x16_f16(p1.v, vf3, oacc1, 0, 0, 0);
    __builtin_amdgcn_s_setprio(0);
    __syncthreads();
  }
#undef STAGE
  // ---- epilogue: combine 4 key-slice partials via LDS (alias of KVl) ----
  lsw += __shfl_xor(lsw, 32, 64);
  if (hi == 0) Lsh[w * 32 + r] = lsw;
#pragma unroll
  for (int dt = 0; dt < 2; ++dt) {
    f16* orow = KVl + w * 2048 + (dt * 32 + r) * 32;
    const f32x16& oa = dt ? oacc1 : oacc0;
#pragma unroll
    for (int u = 0; u < 4; ++u) {
      f16x4 h4;
      h4[0] = (f16)oa[u * 4 + 0]; h4[1] = (f16)oa[u * 4 + 1];
      h4[2] = (f16)oa[u * 4 + 2]; h4[3] = (f16)oa[u * 4 + 3];
      *(f16x4*)(orow + ((u ^ (r & 3)) * 8) + hi * 4) = h4;
    }
  }
  __syncthreads();
  // combine: wave w = (s2 q-16-group-pair, dt2 dd-half, qh2 q-half)
  const int s2 = w >> 2, dt2 = (w >> 1) & 1, qh2 = w & 1;
  const int g = s2 * 2 + hi;    // q 8-group within 32-half
  const int b = bh >> 2, h = bh & 3;
  float accv[8] = {}, denv[8] = {};
#pragma unroll
  for (int ksl = 0; ksl < 4; ++ksl) {
    const int wp = ksl * 2 + qh2;
    f16x8 rd = *(const f16x8*)(KVl + wp * 2048 + (dt2 * 32 + r) * 32 + ((g ^ (r & 3)) * 8));
    f32x4 la = *(const f32x4*)(Lsh + wp * 32 + g * 8);
    f32x4 lb = *(const f32x4*)(Lsh + wp * 32 + g * 8 + 4);
#pragma unroll
    for (int j = 0; j < 4; ++j) {
      accv[j]     += (float)rd[j];
      accv[4 + j] += (float)rd[4 + j];
      denv[j]     += la[j];
      denv[4 + j] += lb[j];
    }
  }
  const int ng = qt * 64 + qh2 * 32 + g * 8;
  const int np = (dt2 * 32 + r) * 64 + h * 16 + (ng >> 8);
  const int cp_ = ng & 255;
  f16x8 yv;
#pragma unroll
  for (int j = 0; j < 8; ++j) yv[j] = (f16)(accv[j] / denv[j]);
  *(f16x8*)(Y + ((size_t)b * 4096 + np) * 256 + cp_) = yv;
}

// ---------------- out-projection GEMM: d_out = Y * w_out^T + b ---------------
__global__ __launch_bounds__(256) void k_out(
    const f16* __restrict__ A, const f16* __restrict__ W,
    float* __restrict__ outF, const float* __restrict__ bias)
{
  __shared__ f16 Al[64 * 40];
  __shared__ f16 Wl[64 * 40];
  const int t = threadIdx.x;
  const int w = t >> 6, l = t & 63;
  const int lrow = l & 15, lk = l >> 4;
  const int m0 = blockIdx.y * 64, nc0 = blockIdx.x * 64;
  f32x4 acc[4] = {};
  const int srow = t >> 2, sseg = t & 3;
  for (int k0 = 0; k0 < 256; k0 += 32) {
    __syncthreads();
    f16x8 av = *(const f16x8*)(A + (size_t)(m0 + srow) * 256 + k0 + sseg * 8);
    f16x8 wv = *(const f16x8*)(W + (size_t)(nc0 + srow) * 256 + k0 + sseg * 8);
    *(f16x8*)(Al + srow * 40 + sseg * 8) = av;
    *(f16x8*)(Wl + srow * 40 + sseg * 8) = wv;
    __syncthreads();
    f16x8 af = *(const f16x8*)(Al + (w * 16 + lrow) * 40 + lk * 8);
#pragma unroll
    for (int ct = 0; ct < 4; ++ct) {
      f16x8 bf = *(const f16x8*)(Wl + (ct * 16 + lrow) * 40 + lk * 8);
      acc[ct] = __builtin_amdgcn_mfma_f32_16x16x32_f16(af, bf, acc[ct], 0, 0, 0);
    }
  }
  const int nb = m0 + w * 16 + lk * 4;
#pragma unroll
  for (int ct = 0; ct < 4; ++ct) {
    int gc = nc0 + ct * 16 + lrow;
    float bv = bias[gc];
#pragma unroll
    for (int j = 0; j < 4; ++j)
      outF[(size_t)(nb + j) * 256 + gc] = acc[ct][j] + bv;
  }
}

extern "C" void kernel_launch(void* const* d_in, const int* in_sizes, int n_in,
                              void* d_out, int out_size, void* d_ws, size_t ws_size,
                              hipStream_t stream)
{
  const float* x     = (const float*)d_in[0];   // [2,4096,256]
  const float* w_qkv = (const float*)d_in[1];   // [768,256]
  const float* w_out = (const float*)d_in[2];   // [256,256]
  const float* b_out = (const float*)d_in[3];   // [256]
  const float* temp  = (const float*)d_in[4];   // [4,1,1]

  char* ws = (char*)d_ws;
  f16*   wqkvb = (f16*)(ws + 4 * 1024 * 1024);
  f16*   woutb = (f16*)(ws + 4 * 1024 * 1024 + 512 * 1024);
  f16*   Qb    = (f16*)(ws + 5  * 1024 * 1024);               // [8][4096][64]
  f16*   Kb    = (f16*)(ws + 9  * 1024 * 1024);
  f16*   Vtb   = (f16*)(ws + 13 * 1024 * 1024);               // [8][64][4096]
  f16*   cqh   = (f16*)(ws + 17 * 1024 * 1024);               // 512 f16
  float* partQ = (float*)(ws + 17 * 1024 * 1024 + 8192);      // 64KB
  float* partK = (float*)(ws + 17 * 1024 * 1024 + 8192 + 131072);
  f16*   Y     = (f16*)(ws + 18 * 1024 * 1024);               // [2][4096][256]
  float* outF  = (float*)d_out;

  k_cvt<<<256, 256, 0, stream>>>(w_qkv, w_out, wqkvb, woutb);
  k_qkv<<<dim3(6, 64), 256, 0, stream>>>(x, wqkvb, Qb, Kb, Vtb, partQ, partK);
  k_norm2<<<1, 512, 0, stream>>>(partQ, partK, temp, cqh);
  k_flash6<<<512, 512, 0, stream>>>(Qb, Kb, Vtb, cqh, Y);
  k_out<<<dim3(4, 128), 256, 0, stream>>>(Y, woutb, outF, b_out);
}

// Round 14
// 82.416 us; speedup vs baseline: 4.1270x; 1.1984x over previous
//
#include <hip/hip_runtime.h>

typedef _Float16 f16;
typedef f16 f16x8 __attribute__((ext_vector_type(8)));
typedef f16 f16x4 __attribute__((ext_vector_type(4)));
typedef __fp16 fp16x2 __attribute__((ext_vector_type(2)));
typedef float f32x4 __attribute__((ext_vector_type(4)));
typedef float f32x16 __attribute__((ext_vector_type(16)));
typedef unsigned int u32;

#define NTOK 4096

// async global->LDS, 16B per lane; dest MUST be wave-uniform (HW: base + lane*16)
#define GLL(gsrc, ldst) \
  __builtin_amdgcn_global_load_lds( \
      (const __attribute__((address_space(1))) void*)(gsrc), \
      (__attribute__((address_space(3))) void*)(ldst), 16, 0, 0)

// ---------------- f32 -> f16 convert (x | w_qkv | w_out) ----------------
__global__ __launch_bounds__(256) void k_cvt(
    const float* __restrict__ x, const float* __restrict__ wq,
    const float* __restrict__ wo,
    f16* __restrict__ xb, f16* __restrict__ wqb, f16* __restrict__ wob)
{
  const int bx = blockIdx.x;
  const float* src; f16* dst; int off;
  if (bx < 2048)      { src = x;  dst = xb;  off = bx * 1024; }
  else if (bx < 2240) { src = wq; dst = wqb; off = (bx - 2048) * 1024; }
  else                { src = wo; dst = wob; off = (bx - 2240) * 1024; }
  const int i = off + threadIdx.x * 4;
  float4 f = *(const float4*)(src + i);
  f16x4 h;
  h[0] = (f16)f.x; h[1] = (f16)f.y; h[2] = (f16)f.z; h[3] = (f16)f.w;
  *(f16x4*)(dst + i) = h;
}

// ---------------- generic C = A[M,K] * W[NC,K]^T MFMA GEMM (round-9 proven) --
// mode 0: QKV epilogue -> scatter Qb/Kb/Vtb + fused norm partials
// mode 1: out epilogue -> d_out f32 + bias
__global__ __launch_bounds__(256) void k_gemm(
    const f16* __restrict__ A, const f16* __restrict__ W,
    int K, int mode,
    f16* __restrict__ Qb, f16* __restrict__ Kb, f16* __restrict__ Vtb,
    float* __restrict__ outF, const float* __restrict__ bias,
    float* __restrict__ partQ, float* __restrict__ partK)
{
  __shared__ f16 Al[64 * 40];
  __shared__ f16 Wl[64 * 40];
  __shared__ float redl[4][64];
  const int t = threadIdx.x;
  const int w = t >> 6, l = t & 63;
  const int lrow = l & 15, lk = l >> 4;
  const int m0 = blockIdx.y * 64, nc0 = blockIdx.x * 64;
  f32x4 acc[4] = {};
  const int srow = t >> 2, sseg = t & 3;
  for (int k0 = 0; k0 < K; k0 += 32) {
    __syncthreads();
    f16x8 av = *(const f16x8*)(A + (size_t)(m0 + srow) * K + k0 + sseg * 8);
    f16x8 wv = *(const f16x8*)(W + (size_t)(nc0 + srow) * K + k0 + sseg * 8);
    *(f16x8*)(Al + srow * 40 + sseg * 8) = av;
    *(f16x8*)(Wl + srow * 40 + sseg * 8) = wv;
    __syncthreads();
    f16x8 af = *(const f16x8*)(Al + (w * 16 + lrow) * 40 + lk * 8);
#pragma unroll
    for (int ct = 0; ct < 4; ++ct) {
      f16x8 bf = *(const f16x8*)(Wl + (ct * 16 + lrow) * 40 + lk * 8);
      acc[ct] = __builtin_amdgcn_mfma_f32_16x16x32_f16(af, bf, acc[ct], 0, 0, 0);
    }
  }
  const int nb = m0 + w * 16 + lk * 4;
  if (mode == 0) {
    const int b = nb >> 12, n = nb & 4095;
#pragma unroll
    for (int ct = 0; ct < 4; ++ct) {
      int gc = nc0 + ct * 16 + lrow;
      int s = gc >> 8, h = (gc >> 6) & 3, dd = gc & 63;
      int bh = b * 4 + h;
      if (s == 2) {
        f16x4 v;
#pragma unroll
        for (int j = 0; j < 4; ++j) v[j] = (f16)acc[ct][j];
        *(f16x4*)(Vtb + ((size_t)bh * 64 + dd) * 4096 + n) = v;
      } else {
        f16* dst = (s == 0) ? Qb : Kb;
#pragma unroll
        for (int j = 0; j < 4; ++j)
          dst[((size_t)bh * 4096 + n + j) * 64 + dd] = (f16)acc[ct][j];
      }
    }
    // fused per-channel squared-sum partials (over this block's 64 tokens)
    if (nc0 < 512) {
#pragma unroll
      for (int ct = 0; ct < 4; ++ct) {
        float v = acc[ct][0] * acc[ct][0] + acc[ct][1] * acc[ct][1]
                + acc[ct][2] * acc[ct][2] + acc[ct][3] * acc[ct][3];
        v += __shfl_xor(v, 16, 64);
        v += __shfl_xor(v, 32, 64);
        if (lk == 0) redl[w][ct * 16 + lrow] = v;
      }
      __syncthreads();
      if (t < 64) {
        float sq = redl[0][t] + redl[1][t] + redl[2][t] + redl[3][t];
        const int s = nc0 >> 8, h2 = (nc0 >> 6) & 3;
        const int b2 = m0 >> 12, mb = (m0 >> 6) & 63;
        float* dst = (s == 0) ? partQ : partK;
        dst[((b2 * 4 + h2) * 64 + mb) * 64 + t] = sq;
      }
    }
  } else {
#pragma unroll
    for (int ct = 0; ct < 4; ++ct) {
      int gc = nc0 + ct * 16 + lrow;
      float bv = bias[gc];
#pragma unroll
      for (int j = 0; j < 4; ++j)
        outF[(size_t)(nb + j) * 256 + gc] = acc[ct][j] + bv;
    }
  }
}

// ---------------- finalize: combined Q-side scale c = temp*log2e/(|q||k|) ----
__global__ __launch_bounds__(512) void k_norm2(
    const float* __restrict__ partQ, const float* __restrict__ partK,
    const float* __restrict__ temp, f16* __restrict__ cqh)
{
  const int t = threadIdx.x;            // 512 = 8 bh * 64 dd
  const int bh = t >> 6, dd = t & 63;
  float sq = 0.f, sk = 0.f;
  for (int s = 0; s < 64; ++s) {
    sq += partQ[(bh * 64 + s) * 64 + dd];
    sk += partK[(bh * 64 + s) * 64 + dd];
  }
  float c = temp[bh & 3] * 1.4426950408889634f /
            (fmaxf(sqrtf(sq), 1e-12f) * fmaxf(sqrtf(sk), 1e-12f));
  cqh[t] = (f16)c;
}

// ---------------- flash attention v6 + co-resident block desync --------------
// QBLK=64, 512 blocks, 2 blocks/CU, 8 waves = 4 ks x 2 qh; K,V LDS dbuf via GLL.
// Round-robin dispatch: CU c of XCD x hosts blocks x+8c and x+8(c+32); the
// second (bit 8 of blockIdx) sleeps ~1920cyc pre-loop so the two blocks' pipe
// bursts (ds_read / VALU / MFMA) interleave instead of phase-colliding.
__device__ inline void plane_swap(u32& a, u32& b) {
  asm volatile("v_permlane32_swap_b32 %0, %1" : "+v"(a), "+v"(b));
}

__global__ __launch_bounds__(512, 4) void k_flash6(
    const f16* __restrict__ Qb, const f16* __restrict__ Kb,
    const f16* __restrict__ Vtb, const f16* __restrict__ cqh,
    f16* __restrict__ Y)
{
  __shared__ f16 KVl[32768];    // 2 x (K 128x64 | V 64x128) = 64KB; epilogue alias
  __shared__ float Lsh[256];    // [w][32 q] row sums
  const int t = threadIdx.x, w = t >> 6, l = t & 63;
  const int r = l & 31, hi = l >> 5;
  const int ks = w >> 1, qh = w & 1;
  const int r7 = r & 7;
  // XCD-bijective swizzle: 512 blocks, each XCD owns one (b,h)
  int nb2 = (blockIdx.x & 7) * 64 + (blockIdx.x >> 3);
  const int bh = nb2 >> 6, qt = nb2 & 63;
  const size_t base = (size_t)bh * NTOK * 64;
  // desync co-resident pair: second CU-slot block delays ~1920 cycles
  if ((blockIdx.x >> 8) & 1) __builtin_amdgcn_s_sleep(30);
  // Q fragments (32 q), scaled by combined per-d factor c
  f16x8 qf0, qf1, qf2, qf3;
  {
    const f16* cq = cqh + bh * 64;
    const f16* qp = Qb + base + (size_t)(qt * 64 + qh * 32 + r) * 64 + hi * 8;
    qf0 = *(const f16x8*)(qp)      * *(const f16x8*)(cq +  0 + hi * 8);
    qf1 = *(const f16x8*)(qp + 16) * *(const f16x8*)(cq + 16 + hi * 8);
    qf2 = *(const f16x8*)(qp + 32) * *(const f16x8*)(cq + 32 + hi * 8);
    qf3 = *(const f16x8*)(qp + 48) * *(const f16x8*)(cq + 48 + hi * 8);
  }
  // staging source pointers (pre-swizzled global addresses, rule #21)
  const f16* srcK = Kb + base + (size_t)(w * 8 + (l >> 3)) * 64 + ((l & 7) ^ (l >> 3)) * 8;
  const int vrow = w * 4 + (l >> 4);
  const f16* srcV = Vtb + base + (size_t)vrow * 4096 + ((l & 15) ^ (vrow & 7)) * 8;
  const int dK = w * 512;
  const int dV = 8192 + w * 512;
#define STAGE(cur, tile) { \
    const f16* sk_ = srcK + (size_t)(tile) * 8192; \
    const f16* sv_ = srcV + (tile) * 128; \
    GLL(sk_,          KVl + (cur) * 16384 + dK); \
    GLL(sk_ + 4096,   KVl + (cur) * 16384 + dK + 4096); \
    GLL(sv_,          KVl + (cur) * 16384 + dV); \
    GLL(sv_ + 131072, KVl + (cur) * 16384 + dV + 4096); }
  // fragment read offsets (f16 units, constant across stages)
  const int kro = (ks * 32 + r) * 64;
  const int kc0 = ((0 + hi) ^ r7) * 8, kc1 = ((2 + hi) ^ r7) * 8;
  const int kc2 = ((4 + hi) ^ r7) * 8, kc3 = ((6 + hi) ^ r7) * 8;
  const int vb0 = 8192 + r * 128, vb1 = 8192 + (32 + r) * 128;
  const int vc0 = ((ks * 4 + 0 + hi) ^ r7) * 8, vc1 = ((ks * 4 + 2 + hi) ^ r7) * 8;

  f32x16 oacc0 = {}, oacc1 = {};
  float lsw = 0.f;
  STAGE(0, 0);
  __syncthreads();
  for (int tl = 0; tl < 32; ++tl) {
    const int cur = tl & 1;
    const f16* Bb = KVl + cur * 16384;
    f16x8 kf0 = *(const f16x8*)(Bb + kro + kc0);
    f16x8 kf1 = *(const f16x8*)(Bb + kro + kc1);
    f16x8 kf2 = *(const f16x8*)(Bb + kro + kc2);
    f16x8 kf3 = *(const f16x8*)(Bb + kro + kc3);
    f16x8 vf0 = *(const f16x8*)(Bb + vb0 + vc0);
    f16x8 vf1 = *(const f16x8*)(Bb + vb0 + vc1);
    f16x8 vf2 = *(const f16x8*)(Bb + vb1 + vc0);
    f16x8 vf3 = *(const f16x8*)(Bb + vb1 + vc1);
    if (tl < 31) STAGE(cur ^ 1, tl + 1);
    // QK^T
    f32x16 sacc = {};
    __builtin_amdgcn_s_setprio(1);
    sacc = __builtin_amdgcn_mfma_f32_32x32x16_f16(kf0, qf0, sacc, 0, 0, 0);
    sacc = __builtin_amdgcn_mfma_f32_32x32x16_f16(kf1, qf1, sacc, 0, 0, 0);
    sacc = __builtin_amdgcn_mfma_f32_32x32x16_f16(kf2, qf2, sacc, 0, 0, 0);
    sacc = __builtin_amdgcn_mfma_f32_32x32x16_f16(kf3, qf3, sacc, 0, 0, 0);
    __builtin_amdgcn_s_setprio(0);
    // softmax in-register: exp2, pack, permlane redistribute
    u32 Dw[8];
#pragma unroll
    for (int u = 0; u < 4; ++u) {
#pragma unroll
      for (int v = 0; v < 2; ++v) {
        float a  = __builtin_amdgcn_exp2f(sacc[u * 4 + v * 2]);
        float b2 = __builtin_amdgcn_exp2f(sacc[u * 4 + v * 2 + 1]);
        lsw += a + b2;
        union { fp16x2 h; u32 u; } cv;
        cv.h = __builtin_amdgcn_cvt_pkrtz(a, b2);
        Dw[u * 2 + v] = cv.u;
      }
    }
    plane_swap(Dw[0], Dw[2]);
    plane_swap(Dw[1], Dw[3]);
    plane_swap(Dw[4], Dw[6]);
    plane_swap(Dw[5], Dw[7]);
    union { f16x8 v; u32 d[4]; } p0, p1;
    p0.d[0] = Dw[0]; p0.d[1] = Dw[1]; p0.d[2] = Dw[2]; p0.d[3] = Dw[3];
    p1.d[0] = Dw[4]; p1.d[1] = Dw[5]; p1.d[2] = Dw[6]; p1.d[3] = Dw[7];
    // PV
    __builtin_amdgcn_s_setprio(1);
    oacc0 = __builtin_amdgcn_mfma_f32_32x32x16_f16(p0.v, vf0, oacc0, 0, 0, 0);
    oacc0 = __builtin_amdgcn_mfma_f32_32x32x16_f16(p1.v, vf1, oacc0, 0, 0, 0);
    oacc1 = __builtin_amdgcn_mfma_f32_32x32x16_f16(p0.v, vf2, oacc1, 0, 0, 0);
    oacc1 = __builtin_amdgcn_mfma_f32_32x32x16_f16(p1.v, vf3, oacc1, 0, 0, 0);
    __builtin_amdgcn_s_setprio(0);
    __syncthreads();
  }
#undef STAGE
  // ---- epilogue: combine 4 key-slice partials via LDS (alias of KVl) ----
  lsw += __shfl_xor(lsw, 32, 64);
  if (hi == 0) Lsh[w * 32 + r] = lsw;
#pragma unroll
  for (int dt = 0; dt < 2; ++dt) {
    f16* orow = KVl + w * 2048 + (dt * 32 + r) * 32;
    const f32x16& oa = dt ? oacc1 : oacc0;
#pragma unroll
    for (int u = 0; u < 4; ++u) {
      f16x4 h4;
      h4[0] = (f16)oa[u * 4 + 0]; h4[1] = (f16)oa[u * 4 + 1];
      h4[2] = (f16)oa[u * 4 + 2]; h4[3] = (f16)oa[u * 4 + 3];
      *(f16x4*)(orow + ((u ^ (r & 3)) * 8) + hi * 4) = h4;
    }
  }
  __syncthreads();
  // combine: wave w = (s2 q-16-group-pair, dt2 dd-half, qh2 q-half)
  const int s2 = w >> 2, dt2 = (w >> 1) & 1, qh2 = w & 1;
  const int g = s2 * 2 + hi;    // q 8-group within 32-half
  const int b = bh >> 2, h = bh & 3;
  float accv[8] = {}, denv[8] = {};
#pragma unroll
  for (int ksl = 0; ksl < 4; ++ksl) {
    const int wp = ksl * 2 + qh2;
    f16x8 rd = *(const f16x8*)(KVl + wp * 2048 + (dt2 * 32 + r) * 32 + ((g ^ (r & 3)) * 8));
    f32x4 la = *(const f32x4*)(Lsh + wp * 32 + g * 8);
    f32x4 lb = *(const f32x4*)(Lsh + wp * 32 + g * 8 + 4);
#pragma unroll
    for (int j = 0; j < 4; ++j) {
      accv[j]     += (float)rd[j];
      accv[4 + j] += (float)rd[4 + j];
      denv[j]     += la[j];
      denv[4 + j] += lb[j];
    }
  }
  const int ng = qt * 64 + qh2 * 32 + g * 8;
  const int np = (dt2 * 32 + r) * 64 + h * 16 + (ng >> 8);
  const int cp_ = ng & 255;
  f16x8 yv;
#pragma unroll
  for (int j = 0; j < 8; ++j) yv[j] = (f16)(accv[j] / denv[j]);
  *(f16x8*)(Y + ((size_t)b * 4096 + np) * 256 + cp_) = yv;
}

extern "C" void kernel_launch(void* const* d_in, const int* in_sizes, int n_in,
                              void* d_out, int out_size, void* d_ws, size_t ws_size,
                              hipStream_t stream)
{
  const float* x     = (const float*)d_in[0];   // [2,4096,256]
  const float* w_qkv = (const float*)d_in[1];   // [768,256]
  const float* w_out = (const float*)d_in[2];   // [256,256]
  const float* b_out = (const float*)d_in[3];   // [256]
  const float* temp  = (const float*)d_in[4];   // [4,1,1]

  char* ws = (char*)d_ws;
  f16*   xb    = (f16*)(ws);                                  // 4MB
  f16*   wqkvb = (f16*)(ws + 4 * 1024 * 1024);
  f16*   woutb = (f16*)(ws + 4 * 1024 * 1024 + 512 * 1024);
  f16*   Qb    = (f16*)(ws + 5  * 1024 * 1024);               // [8][4096][64]
  f16*   Kb    = (f16*)(ws + 9  * 1024 * 1024);
  f16*   Vtb   = (f16*)(ws + 13 * 1024 * 1024);               // [8][64][4096]
  f16*   cqh   = (f16*)(ws + 17 * 1024 * 1024);               // 512 f16
  float* partQ = (float*)(ws + 17 * 1024 * 1024 + 8192);      // 128KB
  float* partK = (float*)(ws + 17 * 1024 * 1024 + 8192 + 131072);
  f16*   Y     = (f16*)(ws + 18 * 1024 * 1024);               // [2][4096][256]
  float* outF  = (float*)d_out;

  k_cvt<<<2304, 256, 0, stream>>>(x, w_qkv, w_out, xb, wqkvb, woutb);
  k_gemm<<<dim3(12, 128), 256, 0, stream>>>(xb, wqkvb, 256, 0, Qb, Kb, Vtb,
                                            nullptr, nullptr, partQ, partK);
  k_norm2<<<1, 512, 0, stream>>>(partQ, partK, temp, cqh);
  k_flash6<<<512, 512, 0, stream>>>(Qb, Kb, Vtb, cqh, Y);
  k_gemm<<<dim3(4, 128), 256, 0, stream>>>(Y, woutb, 256, 1, nullptr, nullptr, nullptr,
                                           outF, b_out, nullptr, nullptr);
}

// Round 15
// 79.940 us; speedup vs baseline: 4.2549x; 1.0310x over previous
//
#include <hip/hip_runtime.h>

typedef _Float16 f16;
typedef f16 f16x8 __attribute__((ext_vector_type(8)));
typedef f16 f16x4 __attribute__((ext_vector_type(4)));
typedef __fp16 fp16x2 __attribute__((ext_vector_type(2)));
typedef float f32x4 __attribute__((ext_vector_type(4)));
typedef float f32x16 __attribute__((ext_vector_type(16)));
typedef unsigned int u32;

#define NTOK 4096

// async global->LDS, 16B per lane; dest MUST be wave-uniform (HW: base + lane*16)
#define GLL(gsrc, ldst) \
  __builtin_amdgcn_global_load_lds( \
      (const __attribute__((address_space(1))) void*)(gsrc), \
      (__attribute__((address_space(3))) void*)(ldst), 16, 0, 0)

// ---------------- f32 -> f16 convert (x | w_qkv | w_out) ----------------
__global__ __launch_bounds__(256) void k_cvt(
    const float* __restrict__ x, const float* __restrict__ wq,
    const float* __restrict__ wo,
    f16* __restrict__ xb, f16* __restrict__ wqb, f16* __restrict__ wob)
{
  const int bx = blockIdx.x;
  const float* src; f16* dst; int off;
  if (bx < 2048)      { src = x;  dst = xb;  off = bx * 1024; }
  else if (bx < 2240) { src = wq; dst = wqb; off = (bx - 2048) * 1024; }
  else                { src = wo; dst = wob; off = (bx - 2240) * 1024; }
  const int i = off + threadIdx.x * 4;
  float4 f = *(const float4*)(src + i);
  f16x4 h;
  h[0] = (f16)f.x; h[1] = (f16)f.y; h[2] = (f16)f.z; h[3] = (f16)f.w;
  *(f16x4*)(dst + i) = h;
}

// ---------------- generic C = A[M,K] * W[NC,K]^T MFMA GEMM (proven) ----------
// mode 0: QKV epilogue -> scatter Qb/Kb/Vtb + fused norm partials
// mode 1: out epilogue -> d_out f32 + bias
__global__ __launch_bounds__(256) void k_gemm(
    const f16* __restrict__ A, const f16* __restrict__ W,
    int K, int mode,
    f16* __restrict__ Qb, f16* __restrict__ Kb, f16* __restrict__ Vtb,
    float* __restrict__ outF, const float* __restrict__ bias,
    float* __restrict__ partQ, float* __restrict__ partK)
{
  __shared__ f16 Al[64 * 40];
  __shared__ f16 Wl[64 * 40];
  __shared__ float redl[4][64];
  const int t = threadIdx.x;
  const int w = t >> 6, l = t & 63;
  const int lrow = l & 15, lk = l >> 4;
  const int m0 = blockIdx.y * 64, nc0 = blockIdx.x * 64;
  f32x4 acc[4] = {};
  const int srow = t >> 2, sseg = t & 3;
  for (int k0 = 0; k0 < K; k0 += 32) {
    __syncthreads();
    f16x8 av = *(const f16x8*)(A + (size_t)(m0 + srow) * K + k0 + sseg * 8);
    f16x8 wv = *(const f16x8*)(W + (size_t)(nc0 + srow) * K + k0 + sseg * 8);
    *(f16x8*)(Al + srow * 40 + sseg * 8) = av;
    *(f16x8*)(Wl + srow * 40 + sseg * 8) = wv;
    __syncthreads();
    f16x8 af = *(const f16x8*)(Al + (w * 16 + lrow) * 40 + lk * 8);
#pragma unroll
    for (int ct = 0; ct < 4; ++ct) {
      f16x8 bf = *(const f16x8*)(Wl + (ct * 16 + lrow) * 40 + lk * 8);
      acc[ct] = __builtin_amdgcn_mfma_f32_16x16x32_f16(af, bf, acc[ct], 0, 0, 0);
    }
  }
  const int nb = m0 + w * 16 + lk * 4;
  if (mode == 0) {
    const int b = nb >> 12, n = nb & 4095;
#pragma unroll
    for (int ct = 0; ct < 4; ++ct) {
      int gc = nc0 + ct * 16 + lrow;
      int s = gc >> 8, h = (gc >> 6) & 3, dd = gc & 63;
      int bh = b * 4 + h;
      if (s == 2) {
        f16x4 v;
#pragma unroll
        for (int j = 0; j < 4; ++j) v[j] = (f16)acc[ct][j];
        *(f16x4*)(Vtb + ((size_t)bh * 64 + dd) * 4096 + n) = v;
      } else {
        f16* dst = (s == 0) ? Qb : Kb;
#pragma unroll
        for (int j = 0; j < 4; ++j)
          dst[((size_t)bh * 4096 + n + j) * 64 + dd] = (f16)acc[ct][j];
      }
    }
    // fused per-channel squared-sum partials (over this block's 64 tokens)
    if (nc0 < 512) {
#pragma unroll
      for (int ct = 0; ct < 4; ++ct) {
        float v = acc[ct][0] * acc[ct][0] + acc[ct][1] * acc[ct][1]
                + acc[ct][2] * acc[ct][2] + acc[ct][3] * acc[ct][3];
        v += __shfl_xor(v, 16, 64);
        v += __shfl_xor(v, 32, 64);
        if (lk == 0) redl[w][ct * 16 + lrow] = v;
      }
      __syncthreads();
      if (t < 64) {
        float sq = redl[0][t] + redl[1][t] + redl[2][t] + redl[3][t];
        const int s = nc0 >> 8, h2 = (nc0 >> 6) & 3;
        const int b2 = m0 >> 12, mb = (m0 >> 6) & 63;
        float* dst = (s == 0) ? partQ : partK;
        dst[((b2 * 4 + h2) * 64 + mb) * 64 + t] = sq;
      }
    }
  } else {
#pragma unroll
    for (int ct = 0; ct < 4; ++ct) {
      int gc = nc0 + ct * 16 + lrow;
      float bv = bias[gc];
#pragma unroll
      for (int j = 0; j < 4; ++j)
        outF[(size_t)(nb + j) * 256 + gc] = acc[ct][j] + bv;
    }
  }
}

// ---------------- flash attention v6 + inline cq (norm2 folded in) -----------
// QBLK=64, 512 blocks, 2 blocks/CU, 8 waves = 4 ks x 2 qh; K,V LDS dbuf via GLL.
// Prologue: each block computes its bh's c[dd] = temp*log2e/(|q||k|) from the
// gemm partials (L2-hot, two-stage LDS reduce into Lsh[0..63]).
__device__ inline void plane_swap(u32& a, u32& b) {
  asm volatile("v_permlane32_swap_b32 %0, %1" : "+v"(a), "+v"(b));
}

__global__ __launch_bounds__(512, 4) void k_flash6(
    const f16* __restrict__ Qb, const f16* __restrict__ Kb,
    const f16* __restrict__ Vtb,
    const float* __restrict__ partQ, const float* __restrict__ partK,
    const float* __restrict__ temp,
    f16* __restrict__ Y)
{
  __shared__ f16 KVl[32768];    // 2 x (K 128x64 | V 64x128) = 64KB; aliased pre/post
  __shared__ float Lsh[256];    // pre-loop: cq[0..63]; epilogue: [w][32 q] row sums
  const int t = threadIdx.x, w = t >> 6, l = t & 63;
  const int r = l & 31, hi = l >> 5;
  const int ks = w >> 1, qh = w & 1;
  const int r7 = r & 7;
  // XCD-bijective swizzle: 512 blocks, each XCD owns one (b,h)
  int nb2 = (blockIdx.x & 7) * 64 + (blockIdx.x >> 3);
  const int bh = nb2 >> 6, qt = nb2 & 63;
  const size_t base = (size_t)bh * NTOK * 64;
  // ---- inline cq: Lsh[dd] = temp[h]*log2e / (|q_dd| * |k_dd|) ----
  {
    float* red = (float*)KVl;            // 2 x 8 parts x 64 dd (4KB alias)
    const int dd = t & 63, part = t >> 6;
    const float* pq = partQ + (size_t)bh * 4096 + part * 512 + dd;
    const float* pk = partK + (size_t)bh * 4096 + part * 512 + dd;
    float sq = 0.f, sk = 0.f;
#pragma unroll
    for (int s = 0; s < 8; ++s) { sq += pq[s * 64]; sk += pk[s * 64]; }
    red[part * 64 + dd] = sq;
    red[512 + part * 64 + dd] = sk;
    __syncthreads();
    if (t < 64) {
      float sq2 = 0.f, sk2 = 0.f;
#pragma unroll
      for (int s = 0; s < 8; ++s) { sq2 += red[s * 64 + t]; sk2 += red[512 + s * 64 + t]; }
      Lsh[t] = temp[bh & 3] * 1.4426950408889634f /
               (fmaxf(sqrtf(sq2), 1e-12f) * fmaxf(sqrtf(sk2), 1e-12f));
    }
    __syncthreads();
  }
  // Q fragments (32 q), scaled by cq (LDS broadcast, f32 mul)
  f16x8 qf0, qf1, qf2, qf3;
  {
    const f16* qp = Qb + base + (size_t)(qt * 64 + qh * 32 + r) * 64 + hi * 8;
#define QLOAD(QF, CH) { f16x8 tmp = *(const f16x8*)(qp + (CH) * 16); \
    _Pragma("unroll") for (int j = 0; j < 8; ++j) \
      QF[j] = (f16)((float)tmp[j] * Lsh[(CH) * 16 + hi * 8 + j]); }
    QLOAD(qf0, 0) QLOAD(qf1, 1) QLOAD(qf2, 2) QLOAD(qf3, 3)
#undef QLOAD
  }
  // staging source pointers (pre-swizzled global addresses, rule #21)
  const f16* srcK = Kb + base + (size_t)(w * 8 + (l >> 3)) * 64 + ((l & 7) ^ (l >> 3)) * 8;
  const int vrow = w * 4 + (l >> 4);
  const f16* srcV = Vtb + base + (size_t)vrow * 4096 + ((l & 15) ^ (vrow & 7)) * 8;
  const int dK = w * 512;
  const int dV = 8192 + w * 512;
#define STAGE(cur, tile) { \
    const f16* sk_ = srcK + (size_t)(tile) * 8192; \
    const f16* sv_ = srcV + (tile) * 128; \
    GLL(sk_,          KVl + (cur) * 16384 + dK); \
    GLL(sk_ + 4096,   KVl + (cur) * 16384 + dK + 4096); \
    GLL(sv_,          KVl + (cur) * 16384 + dV); \
    GLL(sv_ + 131072, KVl + (cur) * 16384 + dV + 4096); }
  // fragment read offsets (f16 units, constant across stages)
  const int kro = (ks * 32 + r) * 64;
  const int kc0 = ((0 + hi) ^ r7) * 8, kc1 = ((2 + hi) ^ r7) * 8;
  const int kc2 = ((4 + hi) ^ r7) * 8, kc3 = ((6 + hi) ^ r7) * 8;
  const int vb0 = 8192 + r * 128, vb1 = 8192 + (32 + r) * 128;
  const int vc0 = ((ks * 4 + 0 + hi) ^ r7) * 8, vc1 = ((ks * 4 + 2 + hi) ^ r7) * 8;

  f32x16 oacc0 = {}, oacc1 = {};
  float lsw = 0.f;
  __syncthreads();   // cq reads done; KVl free for staging
  STAGE(0, 0);
  __syncthreads();
  for (int tl = 0; tl < 32; ++tl) {
    const int cur = tl & 1;
    const f16* Bb = KVl + cur * 16384;
    f16x8 kf0 = *(const f16x8*)(Bb + kro + kc0);
    f16x8 kf1 = *(const f16x8*)(Bb + kro + kc1);
    f16x8 kf2 = *(const f16x8*)(Bb + kro + kc2);
    f16x8 kf3 = *(const f16x8*)(Bb + kro + kc3);
    f16x8 vf0 = *(const f16x8*)(Bb + vb0 + vc0);
    f16x8 vf1 = *(const f16x8*)(Bb + vb0 + vc1);
    f16x8 vf2 = *(const f16x8*)(Bb + vb1 + vc0);
    f16x8 vf3 = *(const f16x8*)(Bb + vb1 + vc1);
    if (tl < 31) STAGE(cur ^ 1, tl + 1);
    // QK^T
    f32x16 sacc = {};
    __builtin_amdgcn_s_setprio(1);
    sacc = __builtin_amdgcn_mfma_f32_32x32x16_f16(kf0, qf0, sacc, 0, 0, 0);
    sacc = __builtin_amdgcn_mfma_f32_32x32x16_f16(kf1, qf1, sacc, 0, 0, 0);
    sacc = __builtin_amdgcn_mfma_f32_32x32x16_f16(kf2, qf2, sacc, 0, 0, 0);
    sacc = __builtin_amdgcn_mfma_f32_32x32x16_f16(kf3, qf3, sacc, 0, 0, 0);
    __builtin_amdgcn_s_setprio(0);
    // softmax in-register: exp2, pack, permlane redistribute
    u32 Dw[8];
#pragma unroll
    for (int u = 0; u < 4; ++u) {
#pragma unroll
      for (int v = 0; v < 2; ++v) {
        float a  = __builtin_amdgcn_exp2f(sacc[u * 4 + v * 2]);
        float b2 = __builtin_amdgcn_exp2f(sacc[u * 4 + v * 2 + 1]);
        lsw += a + b2;
        union { fp16x2 h; u32 u; } cv;
        cv.h = __builtin_amdgcn_cvt_pkrtz(a, b2);
        Dw[u * 2 + v] = cv.u;
      }
    }
    plane_swap(Dw[0], Dw[2]);
    plane_swap(Dw[1], Dw[3]);
    plane_swap(Dw[4], Dw[6]);
    plane_swap(Dw[5], Dw[7]);
    union { f16x8 v; u32 d[4]; } p0, p1;
    p0.d[0] = Dw[0]; p0.d[1] = Dw[1]; p0.d[2] = Dw[2]; p0.d[3] = Dw[3];
    p1.d[0] = Dw[4]; p1.d[1] = Dw[5]; p1.d[2] = Dw[6]; p1.d[3] = Dw[7];
    // PV
    __builtin_amdgcn_s_setprio(1);
    oacc0 = __builtin_amdgcn_mfma_f32_32x32x16_f16(p0.v, vf0, oacc0, 0, 0, 0);
    oacc0 = __builtin_amdgcn_mfma_f32_32x32x16_f16(p1.v, vf1, oacc0, 0, 0, 0);
    oacc1 = __builtin_amdgcn_mfma_f32_32x32x16_f16(p0.v, vf2, oacc1, 0, 0, 0);
    oacc1 = __builtin_amdgcn_mfma_f32_32x32x16_f16(p1.v, vf3, oacc1, 0, 0, 0);
    __builtin_amdgcn_s_setprio(0);
    __syncthreads();
  }
#undef STAGE
  // ---- epilogue: combine 4 key-slice partials via LDS (alias of KVl) ----
  lsw += __shfl_xor(lsw, 32, 64);
  if (hi == 0) Lsh[w * 32 + r] = lsw;
#pragma unroll
  for (int dt = 0; dt < 2; ++dt) {
    f16* orow = KVl + w * 2048 + (dt * 32 + r) * 32;
    const f32x16& oa = dt ? oacc1 : oacc0;
#pragma unroll
    for (int u = 0; u < 4; ++u) {
      f16x4 h4;
      h4[0] = (f16)oa[u * 4 + 0]; h4[1] = (f16)oa[u * 4 + 1];
      h4[2] = (f16)oa[u * 4 + 2]; h4[3] = (f16)oa[u * 4 + 3];
      *(f16x4*)(orow + ((u ^ (r & 3)) * 8) + hi * 4) = h4;
    }
  }
  __syncthreads();
  // combine: wave w = (s2 q-16-group-pair, dt2 dd-half, qh2 q-half)
  const int s2 = w >> 2, dt2 = (w >> 1) & 1, qh2 = w & 1;
  const int g = s2 * 2 + hi;    // q 8-group within 32-half
  const int b = bh >> 2, h = bh & 3;
  float accv[8] = {}, denv[8] = {};
#pragma unroll
  for (int ksl = 0; ksl < 4; ++ksl) {
    const int wp = ksl * 2 + qh2;
    f16x8 rd = *(const f16x8*)(KVl + wp * 2048 + (dt2 * 32 + r) * 32 + ((g ^ (r & 3)) * 8));
    f32x4 la = *(const f32x4*)(Lsh + wp * 32 + g * 8);
    f32x4 lb = *(const f32x4*)(Lsh + wp * 32 + g * 8 + 4);
#pragma unroll
    for (int j = 0; j < 4; ++j) {
      accv[j]     += (float)rd[j];
      accv[4 + j] += (float)rd[4 + j];
      denv[j]     += la[j];
      denv[4 + j] += lb[j];
    }
  }
  const int ng = qt * 64 + qh2 * 32 + g * 8;
  const int np = (dt2 * 32 + r) * 64 + h * 16 + (ng >> 8);
  const int cp_ = ng & 255;
  f16x8 yv;
#pragma unroll
  for (int j = 0; j < 8; ++j) yv[j] = (f16)(accv[j] / denv[j]);
  *(f16x8*)(Y + ((size_t)b * 4096 + np) * 256 + cp_) = yv;
}

extern "C" void kernel_launch(void* const* d_in, const int* in_sizes, int n_in,
                              void* d_out, int out_size, void* d_ws, size_t ws_size,
                              hipStream_t stream)
{
  const float* x     = (const float*)d_in[0];   // [2,4096,256]
  const float* w_qkv = (const float*)d_in[1];   // [768,256]
  const float* w_out = (const float*)d_in[2];   // [256,256]
  const float* b_out = (const float*)d_in[3];   // [256]
  const float* temp  = (const float*)d_in[4];   // [4,1,1]

  char* ws = (char*)d_ws;
  f16*   xb    = (f16*)(ws);                                  // 4MB
  f16*   wqkvb = (f16*)(ws + 4 * 1024 * 1024);
  f16*   woutb = (f16*)(ws + 4 * 1024 * 1024 + 512 * 1024);
  f16*   Qb    = (f16*)(ws + 5  * 1024 * 1024);               // [8][4096][64]
  f16*   Kb    = (f16*)(ws + 9  * 1024 * 1024);
  f16*   Vtb   = (f16*)(ws + 13 * 1024 * 1024);               // [8][64][4096]
  float* partQ = (float*)(ws + 17 * 1024 * 1024 + 8192);      // 128KB
  float* partK = (float*)(ws + 17 * 1024 * 1024 + 8192 + 131072);
  f16*   Y     = (f16*)(ws + 18 * 1024 * 1024);               // [2][4096][256]
  float* outF  = (float*)d_out;

  k_cvt<<<2304, 256, 0, stream>>>(x, w_qkv, w_out, xb, wqkvb, woutb);
  k_gemm<<<dim3(12, 128), 256, 0, stream>>>(xb, wqkvb, 256, 0, Qb, Kb, Vtb,
                                            nullptr, nullptr, partQ, partK);
  k_flash6<<<512, 512, 0, stream>>>(Qb, Kb, Vtb, partQ, partK, temp, Y);
  k_gemm<<<dim3(4, 128), 256, 0, stream>>>(Y, woutb, 256, 1, nullptr, nullptr, nullptr,
                                           outF, b_out, nullptr, nullptr);
}